// Round 7
// baseline (647.628 us; speedup 1.0000x reference)
//
#include <hip/hip_runtime.h>
#include <math.h>

static constexpr int Bsz  = 16384;
static constexpr int Cdim = 1024;
static constexpr int Kdim = 128;
static constexpr int Vdim = 256;
static constexpr int HMd  = 512;
static constexpr int GOUTd= 1536;   // 4*384 gate hidden
static constexpr int GDIM = 1669;
static constexpr int GPAD = 1728;   // 1024 (ctx) + 704 (feats2)
static constexpr int F2D  = 704;    // feats2 width = 11*64
static constexpr int Mdim = 1024;
static constexpr float TAU = 2e-3f; // fp16 score-gap ambiguity threshold (~13 sigma)

typedef __attribute__((ext_vector_type(8))) _Float16 f16x8;
typedef __attribute__((ext_vector_type(4))) _Float16 f16x4;
typedef __attribute__((ext_vector_type(4))) float f32x4;

__device__ __forceinline__ float sigm(float x){ return 1.0f/(1.0f+__expf(-x)); }
// exact-class gelu: erf via A&S 7.1.26 (max erf err 1.5e-7, far below fp16 rounding)
__device__ __forceinline__ float gelu(float x){
    float y = 0.70710678118654752440f * x;
    float a = fabsf(y);
    float t1 = __builtin_amdgcn_rcpf(fmaf(0.3275911f, a, 1.0f));
    float p = t1*fmaf(t1, fmaf(t1, fmaf(t1, fmaf(t1, 1.061405429f, -1.453152027f),
                                         1.421413741f), -0.284496736f), 0.254829592f);
    float e = __expf(-a*a);
    float er = fmaf(-p, e, 1.0f);
    er = (y < 0.0f) ? -er : er;
    return 0.5f*x*(1.0f+er);
}
__device__ __forceinline__ ushort f2h(float f){
    return __builtin_bit_cast(ushort, (_Float16)f);
}

// ============================ prep kernels ============================

__global__ __launch_bounds__(256) void k_zero(int* p){ if (threadIdx.x==0) *p = 0; }

__global__ __launch_bounds__(256) void k_cat(float* __restrict__ dst,
        const float* __restrict__ a, const float* __restrict__ b, int na, int ntot){
    int i = blockIdx.x*256 + threadIdx.x;
    if (i >= ntot) return;
    dst[i] = (i < na) ? a[i] : b[i-na];
}

// f32 [K,N] -> fp16 [N,K] tiled transpose
__global__ __launch_bounds__(256) void k_wt(const float* __restrict__ W,
                                            ushort* __restrict__ Wt, int K, int N){
    __shared__ float tile[64][65];
    int n0 = blockIdx.x*64, k0 = blockIdx.y*64;
    int tx = threadIdx.x & 63, ty = threadIdx.x >> 6;
    #pragma unroll
    for (int i=0;i<64;i+=4)
        tile[ty+i][tx] = W[(size_t)(k0+ty+i)*N + n0 + tx];
    __syncthreads();
    #pragma unroll
    for (int i=0;i<64;i+=4)
        Wt[(size_t)(n0+ty+i)*K + k0 + tx] = f2h(tile[tx][ty+i]);
}

// Wg1 (4,1669,384) -> fp16 [1536, 1728]
__global__ __launch_bounds__(256) void k_wg1t(const float* __restrict__ Wg1,
                                              ushort* __restrict__ Wt){
    __shared__ float tile[64][65];
    int g = blockIdx.z;
    int h0 = blockIdx.x*64, f0 = blockIdx.y*64;
    int tx = threadIdx.x & 63, ty = threadIdx.x >> 6;
    #pragma unroll
    for (int i=0;i<64;i+=4){
        int f = f0+ty+i;
        tile[ty+i][tx] = (f < GDIM) ? Wg1[((size_t)g*GDIM+f)*384 + h0+tx] : 0.0f;
    }
    __syncthreads();
    #pragma unroll
    for (int i=0;i<64;i+=4)
        Wt[((size_t)(g*384 + h0+ty+i))*GPAD + f0+tx] = f2h(tile[tx][ty+i]);
}

// f32 -> fp16 vectorized
__global__ __launch_bounds__(256) void k_cvt(const float* __restrict__ x,
                                             ushort* __restrict__ y, size_t n4){
    size_t i = (size_t)blockIdx.x*256 + threadIdx.x;
    if (i >= n4) return;
    float4 v = ((const float4*)x)[i];
    ushort4 o = { f2h(v.x), f2h(v.y), f2h(v.z), f2h(v.w) };
    ((ushort4*)y)[i] = o;
}

__device__ __forceinline__ void gload_lds16(const void* g, void* l){
    typedef __attribute__((address_space(1))) const unsigned gu32;
    typedef __attribute__((address_space(3))) unsigned lu32;
    __builtin_amdgcn_global_load_lds((gu32*)(unsigned long long)g,
                                     (lu32*)(unsigned)(unsigned long long)l,
                                     16, 0, 0);
}

// ============================ 256x256 8-phase fp16 MFMA GEMM ============================
// 8 waves (512 thr). Wave w: wr2=w>>2 (0..1), wc4=w&3 (0..3).
// Per-wave sub-tile within a 128x128 C-quadrant: 64 rows x 32 cols (4x2 frags).
// LDS ring: A halves [parity][hm] and B halves [parity][hn], 8x8192 fp16 = 128KB.
// Quadrant order per K-tile: (0,0),(1,0),(1,1),(0,1); A-frags reused ph1->ph2, B ph0->ph1, ph2->ph3.
// Half-stream kinds per tile: [B0, A1, A0, B1]; phase q of tile t issues half H_{4t+6+q}.
// Safety: same-parity (2-ahead) stages are B0@ph2 (reads end ph1) and A1@ph3 (reads end ph2);
// next-tile stages (A0@ph0, B1@ph1) target opposite parity. Boundary vmcnt(4) => tile t+1 landed
// (vmcnt(0) at t==nt-2: tail guard shifts outstanding set).
template<int QM, int QN>
__device__ __forceinline__ void do_mfma(f32x4 (&acc)[2][2][4][2],
                                        const f16x8 (&afr)[4][2], const f16x8 (&bfr)[2][2]){
    #pragma unroll
    for (int kk=0;kk<2;kk++)
        #pragma unroll
        for (int mi=0;mi<4;mi++)
            #pragma unroll
            for (int ni=0;ni<2;ni++)
                acc[QM][QN][mi][ni] = __builtin_amdgcn_mfma_f32_16x16x32_f16(
                    afr[mi][kk], bfr[ni][kk], acc[QM][QN][mi][ni], 0, 0, 0);
}

__device__ __forceinline__ void load_afr(const ushort* ldsu, int pt, int qm,
                                         int wr2, int l, f16x8 (&afr)[4][2]){
    const ushort* Ah = ldsu + ((pt<<1)|qm)*8192;
    #pragma unroll
    for (int mi=0;mi<4;mi++){
        int row = wr2*64 + mi*16 + (l & 15);
        #pragma unroll
        for (int kk=0;kk<2;kk++)
            afr[mi][kk] = *(const f16x8*)(const void*)(Ah + row*64 + (((kk*4+(l>>4))^(row&7))<<3));
    }
}
__device__ __forceinline__ void load_bfr(const ushort* ldsu, int pt, int qn,
                                         int wc4, int l, f16x8 (&bfr)[2][2]){
    const ushort* Bh = ldsu + 32768 + ((pt<<1)|qn)*8192;
    #pragma unroll
    for (int ni=0;ni<2;ni++){
        int col = wc4*32 + ni*16 + (l & 15);
        #pragma unroll
        for (int kk=0;kk<2;kk++)
            bfr[ni][kk] = *(const f16x8*)(const void*)(Bh + col*64 + (((kk*4+(l>>4))^(col&7))<<3));
    }
}

// OUTM: 0 = f32 out, 1 = fp16 out, 2 = gate-fused head (part[row][bx*2+slot])
// SRC : 0 = plain (stride lda), 1 = dual source (k<1024 from A stride 1024, else A2 stride 704)
template<int ACT, int OUTM, int SRC, int NX>
__global__ __launch_bounds__(512, 1) void k_mgemm256(const ushort* __restrict__ A,
        const ushort* __restrict__ A2, const ushort* __restrict__ Bt,
        const float* __restrict__ bias, const float* __restrict__ Wg2,
        void* __restrict__ Cout, int K, int lda){
    extern __shared__ char smem[];
    ushort* ldsu = (ushort*)smem;
    int t = threadIdx.x;
    int l = t & 63, wv = t >> 6;
    int wr2 = wv >> 2, wc4 = wv & 3;
    // XCD-aware bijective swizzle
    int nwg = NX * (int)gridDim.y;
    int orig = (int)blockIdx.y * NX + (int)blockIdx.x;
    int qq = nwg >> 3, rr = nwg & 7;
    int xcd = orig & 7, loc = orig >> 3;
    int wgid = (xcd < rr ? xcd*(qq+1) : rr*(qq+1) + (xcd-rr)*qq) + loc;
    int bx = wgid % NX;
    int by = wgid / NX;
    size_t row0 = (size_t)by * 256;
    int col0 = bx * 256;
    constexpr int N = NX*256;
    int nt = K >> 6;

    f32x4 acc[2][2][4][2] = {};
    f16x8 afr[4][2], bfr[2][2];
    int lrow = l >> 3;
    int lc8s = ((l & 7) ^ lrow) << 3;

    // stage one half-tile: 2 gload_lds per thread. kinds: 0=B0,1=A1,2=A0,3=B1
    auto stage_half = [&](int h){
        if (h >= 4*nt) return;
        int k  = h & 3;
        int tau = h >> 2;
        int p  = tau & 1;
        int k0 = tau << 6;
        if (k == 0 || k == 3){          // B half
            int hn = (k == 3);
            ushort* dst = ldsu + 32768 + ((p<<1)|hn)*8192;
            size_t rbase = (size_t)col0 + hn*128;
            #pragma unroll
            for (int i=0;i<2;i++){
                int ch = i*8 + wv;
                int r  = ch*8 + lrow;
                gload_lds16(Bt + (rbase + r)*(size_t)K + k0 + lc8s, dst + ch*512);
            }
        } else {                        // A half
            int hm = (k == 1);
            ushort* dst = ldsu + ((p<<1)|hm)*8192;
            const ushort* Ag; size_t astr; int koff;
            if (SRC == 1){
                if (k0 < 1024){ Ag = A;  astr = 1024; koff = k0; }
                else          { Ag = A2; astr = F2D;  koff = k0 - 1024; }
            } else { Ag = A; astr = (size_t)lda; koff = k0; }
            size_t rbase = row0 + (size_t)hm*128;
            #pragma unroll
            for (int i=0;i<2;i++){
                int ch = i*8 + wv;
                int r  = ch*8 + lrow;
                gload_lds16(Ag + (rbase + r)*astr + koff + lc8s, dst + ch*512);
            }
        }
    };

    // prologue: halves H0..H5 (tile0 all + tile1's B0,A1), then wait tile0 (8 loads retired)
    for (int h = 0; h < 6; ++h) stage_half(h);
    asm volatile("s_waitcnt vmcnt(4)" ::: "memory");
    __builtin_amdgcn_s_barrier();

    for (int tt = 0; tt < nt; ++tt){
        int pt = tt & 1;
        int hb = 4*tt + 6;
        // ---- phase 0: quadrant (0,0) ----
        load_afr(ldsu, pt, 0, wr2, l, afr);
        load_bfr(ldsu, pt, 0, wc4, l, bfr);
        stage_half(hb+0);                       // A0 of tile t+1 (other parity)
        __builtin_amdgcn_s_barrier();
        __builtin_amdgcn_s_setprio(1);
        do_mfma<0,0>(acc, afr, bfr);
        __builtin_amdgcn_s_setprio(0);
        __builtin_amdgcn_s_barrier();
        // ---- phase 1: quadrant (1,0), B reused ----
        load_afr(ldsu, pt, 1, wr2, l, afr);
        stage_half(hb+1);                       // B1 of tile t+1 (other parity)
        __builtin_amdgcn_s_barrier();
        __builtin_amdgcn_s_setprio(1);
        do_mfma<1,0>(acc, afr, bfr);
        __builtin_amdgcn_s_setprio(0);
        __builtin_amdgcn_s_barrier();
        // ---- phase 2: quadrant (1,1), A reused ----
        load_bfr(ldsu, pt, 1, wc4, l, bfr);
        stage_half(hb+2);                       // B0 of tile t+2 (same parity; B0 reads ended ph1)
        __builtin_amdgcn_s_barrier();
        __builtin_amdgcn_s_setprio(1);
        do_mfma<1,1>(acc, afr, bfr);
        __builtin_amdgcn_s_setprio(0);
        __builtin_amdgcn_s_barrier();
        // ---- phase 3: quadrant (0,1), B reused ----
        load_afr(ldsu, pt, 0, wr2, l, afr);
        stage_half(hb+3);                       // A1 of tile t+2 (same parity; A1 reads ended ph2)
        __builtin_amdgcn_s_barrier();
        __builtin_amdgcn_s_setprio(1);
        do_mfma<0,1>(acc, afr, bfr);
        __builtin_amdgcn_s_setprio(0);
        if (tt == nt-2) asm volatile("s_waitcnt vmcnt(0)" ::: "memory");
        else            asm volatile("s_waitcnt vmcnt(4)" ::: "memory");
        __builtin_amdgcn_s_barrier();
    }

    // epilogue. C/D layout: col = l&15, row = (l>>4)*4 + i
    int q4 = l >> 4, cf = l & 15;
    if (OUTM == 2){
        __syncthreads();
        float* sacc = (float*)ldsu;             // [256][2]
        sacc[t] = 0.f;
        __syncthreads();
        int g_lo = col0 / 384;
        #pragma unroll
        for (int qm=0;qm<2;qm++)
        #pragma unroll
        for (int qn=0;qn<2;qn++)
        #pragma unroll
        for (int mi=0;mi<4;mi++)
        #pragma unroll
        for (int ni=0;ni<2;ni++){
            int col_l = qn*128 + wc4*32 + ni*16 + cf;
            int colg  = col0 + col_l;
            int slot  = (colg/384 == g_lo) ? 0 : 1;
            float wg  = Wg2[colg];
            float bv  = bias[colg];
            #pragma unroll
            for (int i=0;i<4;i++){
                int row_l = qm*128 + wr2*64 + mi*16 + q4*4 + i;
                float z = acc[qm][qn][mi][ni][i] + bv;
                atomicAdd(&sacc[row_l*2 + slot], gelu(z)*wg);
            }
        }
        __syncthreads();
        if (t < 256){
            ((float*)Cout)[(row0 + t)*(NX*2) + bx*2 + 0] = sacc[t*2];
            ((float*)Cout)[(row0 + t)*(NX*2) + bx*2 + 1] = sacc[t*2+1];
        }
    } else {
        #pragma unroll
        for (int qm=0;qm<2;qm++)
        #pragma unroll
        for (int qn=0;qn<2;qn++)
        #pragma unroll
        for (int mi=0;mi<4;mi++)
        #pragma unroll
        for (int ni=0;ni<2;ni++){
            int col = col0 + qn*128 + wc4*32 + ni*16 + cf;
            float bv = bias[col];
            #pragma unroll
            for (int i=0;i<4;i++){
                size_t r = row0 + qm*128 + wr2*64 + mi*16 + q4*4 + i;
                float v = acc[qm][qn][mi][ni][i] + bv;
                if (ACT == 1) v = gelu(v);
                if (OUTM == 1) ((ushort*)Cout)[r*N + col] = f2h(v);
                else           ((float*) Cout)[r*N + col] = v;
            }
        }
    }
}

// ============================ 128x128 fp16 MFMA GEMM (L2 only) ============================
template<int ACT, int OUTM, int SRC, int NX>
__global__ __launch_bounds__(256) void k_mgemm(const ushort* __restrict__ A,
        const ushort* __restrict__ A2, const ushort* __restrict__ Bt,
        const float* __restrict__ bias, const float* __restrict__ Wg2,
        void* __restrict__ Cout, int K, int lda){
    __shared__ alignas(16) ushort lds[32768];
    int t = threadIdx.x;
    int l = t & 63, w = t >> 6;
    int wm = w >> 1, wn = w & 1;
    int nwg = NX * (int)gridDim.y;
    int orig = (int)blockIdx.y * NX + (int)blockIdx.x;
    int qq = nwg >> 3, rr = nwg & 7;
    int xcd = orig & 7, loc = orig >> 3;
    int wgid = (xcd < rr ? xcd*(qq+1) : rr*(qq+1) + (xcd-rr)*qq) + loc;
    int bx = wgid % NX;
    int by = wgid / NX;
    size_t row0 = (size_t)by * 128;
    int col0 = bx * 128;
    constexpr int N = NX*128;
    f32x4 acc[4][4] = {};
    int lrow = l >> 3;
    int lc8  = (l & 7) ^ lrow;
    int nt = K >> 6;

    auto stage = [&](int buf, int k0){
        const ushort* Ag; size_t astr; int koff;
        if (SRC == 2){
            Ag = A; astr = (size_t)lda; koff = k0 + (bx ? 512 : 0);
        } else { Ag = A; astr = (size_t)lda; koff = k0; }
        ushort* As = lds + buf*16384;
        ushort* Bs = As + 8192;
        #pragma unroll
        for (int i = 0; i < 4; ++i){
            int ch = w*4 + i;
            int r  = ch*8 + lrow;
            gload_lds16(Ag + (row0 + r)*astr + koff + lc8*8, As + ch*512);
            gload_lds16(Bt + (size_t)(col0 + r)*K + k0 + lc8*8, Bs + ch*512);
        }
    };
    auto compute = [&](int buf){
        const ushort* As = lds + buf*16384;
        const ushort* Bs = As + 8192;
        #pragma unroll
        for (int kk = 0; kk < 2; ++kk){
            f16x8 af[4], bfr[4];
            int j8 = kk*4 + (l >> 4);
            #pragma unroll
            for (int m = 0; m < 4; ++m){
                int row = wm*64 + m*16 + (l & 15);
                int c16 = j8 ^ (row & 7);
                af[m] = *(const f16x8*)(const void*)(As + row*64 + c16*8);
            }
            #pragma unroll
            for (int n = 0; n < 4; ++n){
                int rowb = wn*64 + n*16 + (l & 15);
                int c16 = j8 ^ (rowb & 7);
                bfr[n] = *(const f16x8*)(const void*)(Bs + rowb*64 + c16*8);
            }
            #pragma unroll
            for (int m = 0; m < 4; ++m)
                #pragma unroll
                for (int n = 0; n < 4; ++n)
                    acc[m][n] = __builtin_amdgcn_mfma_f32_16x16x32_f16(af[m], bfr[n], acc[m][n], 0, 0, 0);
        }
    };

    stage(0, 0);
    for (int tt = 0; tt < nt-1; ++tt){
        __builtin_amdgcn_s_barrier();
        stage((tt+1)&1, (tt+1)<<6);
        asm volatile("s_waitcnt vmcnt(8)" ::: "memory");
        __builtin_amdgcn_s_barrier();
        compute(tt&1);
    }
    asm volatile("s_waitcnt vmcnt(0)" ::: "memory");
    __builtin_amdgcn_s_barrier();
    compute((nt-1)&1);

    int q = l >> 4, cf = l & 15;
    #pragma unroll
    for (int m = 0; m < 4; ++m){
        #pragma unroll
        for (int n = 0; n < 4; ++n){
            int col = col0 + wn*64 + n*16 + cf;
            float bv = bias[col];
            #pragma unroll
            for (int i = 0; i < 4; ++i){
                size_t r = row0 + wm*64 + m*16 + q*4 + i;
                float v = acc[m][n][i] + bv;
                if (ACT == 1) v = gelu(v);
                if (OUTM == 1) ((ushort*)Cout)[r*N + col] = f2h(v);
                else           ((float*) Cout)[r*N + col] = v;
            }
        }
    }
}

// ============================ f32 GEMM, dynamic M (fix path) ============================
template<int ACT>
__global__ __launch_bounds__(256) void k_gemm_dyn(const float* __restrict__ A,
                                                  const float* __restrict__ W,
                                                  const float* __restrict__ bias,
                                                  float* __restrict__ C,
                                                  const int* __restrict__ cntp,
                                                  int N, int K){
    int M = (*cntp + 63) & ~63;
    size_t row0 = (size_t)blockIdx.y * 64;
    if ((int)row0 >= M) return;
    __shared__ float As[32][68];
    __shared__ float Ws[32][64];
    int t  = threadIdx.x;
    int tx = t & 15, ty = t >> 4;
    int col0 = blockIdx.x * 64;
    float acc[4][4] = {};
    int ra = t >> 3;
    int ca = (t & 7) << 2;
    int rw = t >> 4;
    int cw = (t & 15) << 2;
    for (int k0 = 0; k0 < K; k0 += 32){
        float4 a0 = *(const float4*)(A + (row0 + ra)*K + k0 + ca);
        float4 a1 = *(const float4*)(A + (row0 + ra + 32)*K + k0 + ca);
        float4 w0 = *(const float4*)(W + (size_t)(k0 + rw)*N + col0 + cw);
        float4 w1 = *(const float4*)(W + (size_t)(k0 + rw + 16)*N + col0 + cw);
        As[ca+0][ra] = a0.x; As[ca+1][ra] = a0.y; As[ca+2][ra] = a0.z; As[ca+3][ra] = a0.w;
        As[ca+0][ra+32] = a1.x; As[ca+1][ra+32] = a1.y; As[ca+2][ra+32] = a1.z; As[ca+3][ra+32] = a1.w;
        *(float4*)&Ws[rw][cw]    = w0;
        *(float4*)&Ws[rw+16][cw] = w1;
        __syncthreads();
        #pragma unroll
        for (int kk = 0; kk < 32; ++kk){
            float4 av = *(const float4*)&As[kk][ty*4];
            float4 wv = *(const float4*)&Ws[kk][tx*4];
            float a4[4] = {av.x, av.y, av.z, av.w};
            float w4[4] = {wv.x, wv.y, wv.z, wv.w};
            #pragma unroll
            for (int i=0;i<4;i++)
                #pragma unroll
                for (int j=0;j<4;j++)
                    acc[i][j] = fmaf(a4[i], w4[j], acc[i][j]);
        }
        __syncthreads();
    }
    #pragma unroll
    for (int i=0;i<4;i++){
        size_t r = row0 + ty*4 + i;
        #pragma unroll
        for (int j=0;j<4;j++){
            int c = col0 + tx*4 + j;
            float v = acc[i][j] + bias[c];
            if (ACT == 1) v = gelu(v);
            C[r*N + c] = v;
        }
    }
}

// gather flagged ctx rows -> fctx (f32), zero-pad to multiple of 64 rows
__global__ __launch_bounds__(256) void k_gather(const float* __restrict__ ctx,
        const int* __restrict__ flaglist, const int* __restrict__ flagcnt,
        float* __restrict__ fctx, int b0){
    int i = (blockIdx.x<<2) + (threadIdx.x>>6);
    int lane = threadIdx.x & 63;
    int cnt = *flagcnt;
    int cntpad = (cnt + 63) & ~63;
    if (i >= cntpad) return;
    float4* dst = (float4*)(fctx + (size_t)i*1024);
    if (i < cnt){
        const float4* src = (const float4*)(ctx + ((size_t)b0 + flaglist[i])*1024);
        #pragma unroll
        for (int j=0;j<4;j++) dst[lane + 64*j] = src[lane + 64*j];
    } else {
        float4 z = {0.f,0.f,0.f,0.f};
        #pragma unroll
        for (int j=0;j<4;j++) dst[lane + 64*j] = z;
    }
}

// per flagged row: normalize exact ck, rescore, patch ckc/feats2/bidx
__global__ __launch_bounds__(256) void k_fixapply(const float* __restrict__ fck,
        const float* __restrict__ keys, const float* __restrict__ values,
        const float* __restrict__ age,  const float* __restrict__ alive,
        float* __restrict__ ckc, ushort* __restrict__ feats2, int* __restrict__ bidx,
        const int* __restrict__ flagcnt, const int* __restrict__ flaglist, int b0){
    int i = (blockIdx.x<<2) + (threadIdx.x>>6);
    int lane = threadIdx.x & 63;
    if (i >= *flagcnt) return;
    int w = flaglist[i];
    size_t b = (size_t)b0 + w;
    float2 c2 = ((const float2*)(fck + (size_t)i*128))[lane];
    float ss = c2.x*c2.x + c2.y*c2.y;
    #pragma unroll
    for (int o=32;o;o>>=1) ss += __shfl_xor(ss,o);
    float inv = 1.0f / fmaxf(sqrtf(ss), 1e-6f);
    float2 cc; cc.x = c2.x*inv; cc.y = c2.y*inv;
    ((float2*)(ckc + (size_t)w*128))[lane] = cc;
    ushort* f2 = feats2 + (size_t)w*F2D;
    { ushort2 o = { f2h(cc.x), f2h(cc.y) };
      ((ushort2*)f2)[lane] = o; }
    float s1v = -1e30f; int bi = 0; int anylive = 0;
    #pragma unroll
    for (int s=0;s<6;s++){
        float a = alive[b*6+s];
        float2 k2 = ((const float2*)(keys + (b*6+s)*128))[lane];
        float ks = k2.x*k2.x + k2.y*k2.y;
        float dt = cc.x*k2.x + cc.y*k2.y;
        #pragma unroll
        for (int o=32;o;o>>=1){ ks += __shfl_xor(ks,o); dt += __shfl_xor(dt,o); }
        float sc;
        if (a > 0.0f){ sc = dt / fmaxf(sqrtf(ks), 1e-6f); anylive = 1; }
        else sc = -1e4f;
        if (sc > s1v){ s1v = sc; bi = s; }
    }
    int bis = anylive ? bi : 0;
    float bsc = anylive ? s1v : 0.0f;
    float4 mv = ((const float4*)(values + (b*6+bis)*256))[lane];
    ushort4 mo = { f2h(mv.x), f2h(mv.y), f2h(mv.z), f2h(mv.w) };
    ((ushort4*)(f2+384))[lane] = mo;
    if (lane == 0){
        bidx[w] = bis;
        float mage = age[b*6 + bis];
        f2[640] = f2h(bsc);
        f2[641] = f2h(sigm((mage - 8.0f)*0.125f));
        f2[642] = f2h(1.0f - bsc);
    }
}

// ---- slot match + feats2 build + ambiguity flagging ----
__global__ __launch_bounds__(256) void k_feats(
        const float* __restrict__ ledger, const float* __restrict__ keys,
        const float* __restrict__ values, const float* __restrict__ age,
        const float* __restrict__ alive,  const float* __restrict__ ckv,
        float* __restrict__ ckc, ushort* __restrict__ feats2,
        int* __restrict__ bidx, int* __restrict__ flagcnt, int* __restrict__ flaglist,
        int b0){
    int w = (blockIdx.x<<2) + (threadIdx.x>>6);
    int lane = threadIdx.x & 63;
    size_t b = (size_t)b0 + w;
    const float* ckr = ckv + (size_t)w*384;
    float2 cr2 = ((const float2*)ckr)[lane];
    float ssc = cr2.x*cr2.x + cr2.y*cr2.y;
    #pragma unroll
    for (int o=32;o;o>>=1) ssc += __shfl_xor(ssc,o);
    float invc = 1.0f / fmaxf(sqrtf(ssc), 1e-6f);
    float2 cc; cc.x = cr2.x*invc; cc.y = cr2.y*invc;
    ((float2*)(ckc + (size_t)w*128))[lane] = cc;
    float s1v = -1e30f, s2v = -1e30f; int bi = 0; int anylive = 0;
    #pragma unroll
    for (int s=0;s<6;s++){
        float a = alive[b*6+s];
        float2 k2 = ((const float2*)(keys + (b*6+s)*128))[lane];
        float ss = k2.x*k2.x + k2.y*k2.y;
        float dt = cc.x*k2.x + cc.y*k2.y;
        #pragma unroll
        for (int o=32;o;o>>=1){ ss += __shfl_xor(ss,o); dt += __shfl_xor(dt,o); }
        float sc;
        if (a > 0.0f){ sc = dt / fmaxf(sqrtf(ss), 1e-6f); anylive = 1; }
        else sc = -1e4f;
        if (sc > s1v){ s2v = s1v; s1v = sc; bi = s; }
        else if (sc > s2v) s2v = sc;
    }
    float best_score = anylive ? s1v : 0.0f;
    int bis = anylive ? bi : 0;
    if (lane == 0 && (s1v - s2v) < TAU){
        int pos = atomicAdd(flagcnt, 1);
        flaglist[pos] = w;
    }
    float4 mv = ((const float4*)(values + (b*6+bis)*256))[lane];
    float mage = age[b*6+bis];
    float cad = sigm((mage - 8.0f)*0.125f);
    ushort* f2 = feats2 + (size_t)w*F2D;
    { ushort2 o = { f2h(cc.x), f2h(cc.y) };
      ((ushort2*)f2)[lane] = o; }
    { float4 v = ((const float4*)(ckr+128))[lane];
      ushort4 o = { f2h(v.x), f2h(v.y), f2h(v.z), f2h(v.w) };
      ((ushort4*)(f2+128))[lane] = o; }
    { ushort4 o = { f2h(mv.x), f2h(mv.y), f2h(mv.z), f2h(mv.w) };
      ((ushort4*)(f2+384))[lane] = o; }
    if (lane == 0){
        f2[640] = f2h(best_score);
        f2[641] = f2h(cad);
        f2[642] = f2h(1.0f - best_score);
        f2[643] = f2h(ledger[b*2]);
        f2[644] = f2h(ledger[b*2+1]);
        bidx[w] = bis;
    }
    if (lane < GPAD - GDIM) f2[645+lane] = 0;
}

// ---- gates (from part), spawn select, scatter update, summary ----
// part layout: [row][12] with slot j=bx*2+s, gate_of = {0,0, 0,1, 1,1, 2,2, 2,3, 3,3}
__global__ __launch_bounds__(256) void k_update(const float* __restrict__ keys,
        const float* __restrict__ values, const float* __restrict__ conf,
        const float* __restrict__ age,    const float* __restrict__ alive,
        const float* __restrict__ ckC,    const float* __restrict__ ckv,
        const float* __restrict__ part,   const float* __restrict__ bg2,
        const int* __restrict__ bidx,
        float* __restrict__ probsC,
        float* __restrict__ o_keys, float* __restrict__ o_vals,
        float* __restrict__ o_conf, float* __restrict__ o_age,
        float* __restrict__ o_aliv, float* __restrict__ o_sum,
        ushort* __restrict__ o_sumb, int b0){
    int w = (blockIdx.x<<2) + (threadIdx.x>>6);
    int lane = threadIdx.x & 63;
    size_t b = (size_t)b0 + w;
    const float* pp = part + (size_t)w*12;
    const int gate_of[12] = {0,0, 0,1, 1,1, 2,2, 2,3, 3,3};
    float ga[4] = {bg2[0], bg2[1], bg2[2], bg2[3]};
    #pragma unroll
    for (int j=0;j<12;j++) ga[gate_of[j]] += pp[j];
    float pb[4];
    #pragma unroll
    for (int g=0; g<4; ++g) pb[g] = sigm(ga[g]);
    if (lane < 4) probsC[w*4 + lane] = pb[lane];
    float rp = pb[0], sp = pb[1], tp = pb[3];
    float al[6], cf[6], ag[6];
    float hl = 0.f;
    #pragma unroll
    for (int s=0;s<6;s++){
        al[s]=alive[b*6+s]; cf[s]=conf[b*6+s]; ag[s]=age[b*6+s];
        hl = fmaxf(hl, al[s]);
    }
    float rr = hl * sigm((rp-0.55f)*4.0f);
    float sr = sigm((sp-0.60f)*4.0f);
    float den = 1.0f + rr + sr;
    float refresh = rr/den, spawn = sr/den;
    float retire = sigm((tp-0.15f)*4.0f);
    int bi = bidx[w];
    int ic = -1;
    #pragma unroll
    for (int s=5;s>=0;s--) if (al[s] < 0.5f) ic = s;
    int si;
    if (ic >= 0) si = ic;
    else {
        float bu = 1e30f; int am = 0;
        #pragma unroll
        for (int s=0;s<6;s++){
            float u = (s == bi) ? 1e4f : (cf[s] - 0.01f*ag[s]);
            if (u < bu){ bu = u; am = s; }
        }
        si = am;
    }
    float2 cc  = ((const float2*)(ckC + (size_t)w*128))[lane];
    float4 cvv = ((const float4*)(ckv + (size_t)w*384 + 128))[lane];
    float s0=0,s1=0,s2=0,s3=0, wsum=0;
    #pragma unroll
    for (int s=0;s<6;s++){
        float wr = refresh*(s==bi ? 1.0f:0.0f) + spawn*(s==si ? 1.0f:0.0f);
        wr = fminf(wr, 1.0f);
        float rs = (s==bi) ? retire : 0.0f;
        float om = 1.0f - wr;
        float2 k2 = ((const float2*)(keys + (b*6+s)*128))[lane];
        float2 kn; kn.x = k2.x*om + wr*cc.x; kn.y = k2.y*om + wr*cc.y;
        ((float2*)(o_keys + (b*6+s)*128))[lane] = kn;
        float4 vv = ((const float4*)(values + (b*6+s)*256))[lane];
        float4 vn;
        vn.x = vv.x*om + wr*cvv.x; vn.y = vv.y*om + wr*cvv.y;
        vn.z = vv.z*om + wr*cvv.z; vn.w = vv.w*om + wr*cvv.w;
        ((float4*)(o_vals + (b*6+s)*256))[lane] = vn;
        float cn  = (cf[s]*0.995f*om + wr) * (1.0f - rs);
        float an  = fminf(fmaxf(al[s]*(1.0f - rs) + wr, 0.0f), 1.0f);
        float agn = (ag[s] + al[s]) * om;
        float wgt = an * cn;
        wsum += wgt;
        s0 += vn.x*wgt; s1 += vn.y*wgt; s2 += vn.z*wgt; s3 += vn.w*wgt;
        if (lane == s){ o_conf[b*6+s] = cn; o_age[b*6+s] = agn; o_aliv[b*6+s] = an; }
    }
    float inv = 1.0f/(wsum + 1e-6f);
    float4 sm; sm.x = s0*inv; sm.y = s1*inv; sm.z = s2*inv; sm.w = s3*inv;
    ((float4*)(o_sum + b*256))[lane] = sm;
    ushort4 sb = { f2h(sm.x), f2h(sm.y), f2h(sm.z), f2h(sm.w) };
    ((ushort4*)(o_sumb + (size_t)w*256))[lane] = sb;
}

// ---- layernorm + promote (fp16 z in) ----
__global__ __launch_bounds__(256) void k_ln(const ushort* __restrict__ z,
        const float* __restrict__ probs, const float* __restrict__ g_ln,
        const float* __restrict__ b_ln,  float* __restrict__ o_prom, int b0){
    int w = blockIdx.x; int t = threadIdx.x;
    int lane = t & 63, wid = t >> 6;
    f16x4 hv = ((const f16x4*)(z + (size_t)w*1024))[t];
    float v0 = (float)hv[0], v1 = (float)hv[1], v2 = (float)hv[2], v3 = (float)hv[3];
    float s = v0+v1+v2+v3;
    #pragma unroll
    for (int o=32;o;o>>=1) s += __shfl_xor(s,o);
    __shared__ float red[4];
    if (lane==0) red[wid] = s;
    __syncthreads();
    float mu = (red[0]+red[1]+red[2]+red[3]) * (1.0f/1024.0f);
    float d0=v0-mu, d1=v1-mu, d2=v2-mu, d3=v3-mu;
    float ss = d0*d0+d1*d1+d2*d2+d3*d3;
    #pragma unroll
    for (int o=32;o;o>>=1) ss += __shfl_xor(ss,o);
    __syncthreads();
    if (lane==0) red[wid] = ss;
    __syncthreads();
    float var = (red[0]+red[1]+red[2]+red[3]) * (1.0f/1024.0f);
    float rstd = 1.0f / sqrtf(var + 1e-5f);
    float pm = sigm((probs[w*4+2]-0.50f)*4.0f);
    float4 g  = ((const float4*)g_ln)[t];
    float4 bb = ((const float4*)b_ln)[t];
    float4 o;
    o.x = pm*(d0*rstd*g.x + bb.x);
    o.y = pm*(d1*rstd*g.y + bb.y);
    o.z = pm*(d2*rstd*g.z + bb.z);
    o.w = pm*(d3*rstd*g.w + bb.w);
    ((float4*)(o_prom + ((size_t)b0 + w)*1024))[t] = o;
}

extern "C" void kernel_launch(void* const* d_in, const int* in_sizes, int n_in,
                              void* d_out, int out_size, void* d_ws, size_t ws_size,
                              hipStream_t stream){
    const float* ctx    = (const float*)d_in[0];
    const float* ledger = (const float*)d_in[1];
    const float* keys   = (const float*)d_in[2];
    const float* values = (const float*)d_in[3];
    const float* conf   = (const float*)d_in[4];
    const float* age    = (const float*)d_in[5];
    const float* alive  = (const float*)d_in[6];
    const float* Wk1 = (const float*)d_in[7];  const float* bk1 = (const float*)d_in[8];
    const float* Wk2 = (const float*)d_in[9];  const float* bk2 = (const float*)d_in[10];
    const float* Wv1 = (const float*)d_in[11]; const float* bv1 = (const float*)d_in[12];
    const float* Wv2 = (const float*)d_in[13]; const float* bv2 = (const float*)d_in[14];
    const float* Wg1 = (const float*)d_in[15]; const float* bg1 = (const float*)d_in[16];
    const float* Wg2 = (const float*)d_in[17]; const float* bg2 = (const float*)d_in[18];
    const float* Wsum= (const float*)d_in[19]; const float* bsum= (const float*)d_in[20];
    const float* g_ln= (const float*)d_in[21]; const float* b_ln= (const float*)d_in[22];

    float* out   = (float*)d_out;
    float* o_prom= out;
    float* o_sum = o_prom + (size_t)Bsz*Mdim;
    float* o_keys= o_sum  + (size_t)Bsz*Vdim;
    float* o_vals= o_keys + (size_t)Bsz*6*Kdim;
    float* o_conf= o_vals + (size_t)Bsz*6*Vdim;
    float* o_age = o_conf + (size_t)Bsz*6;
    float* o_aliv= o_age  + (size_t)Bsz*6;

    // ---------- workspace layout ----------
    char* p = (char*)d_ws;
    auto alloc = [&](size_t bytes)->char*{
        char* r = p; p += (bytes + 255) & ~(size_t)255; return r;
    };
    ushort* ctxh  = (ushort*)alloc((size_t)Bsz*Cdim*2);          // fp16 ctx
    ushort* W1m   = (ushort*)alloc((size_t)1024*Cdim*2);         // [Wk1t|Wv1t]
    ushort* W2m   = (ushort*)alloc((size_t)384*HMd*2);           // [Wk2t|Wv2t]
    ushort* Wg1tt = (ushort*)alloc((size_t)GOUTd*GPAD*2);
    ushort* Wsumt = (ushort*)alloc((size_t)Mdim*Vdim*2);
    float*  biasm1= (float*) alloc(1024*4);
    float*  biasm2= (float*) alloc(384*4);
    size_t fixed = (size_t)(p - (char*)d_ws);
    size_t per_row = 2048 + 1536 + 512 + 1408 + 48 + 4096 + 512 + 16
                   + 4 + 4 + 2048 + 512 + 128;
    int CB = 16384;
    while (CB > 256 && fixed + (size_t)CB*per_row + 16384 > ws_size) CB >>= 1;
    ushort* H      = (ushort*)alloc((size_t)CB*1024*2);   // [Hk|Hv] fp16
    float*  ckv    = (float*) alloc((size_t)CB*384*4);    // [ckraw|cv] f32
    float*  ckc    = (float*) alloc((size_t)CB*Kdim*4);
    ushort* feats2 = (ushort*)alloc((size_t)CB*F2D*2);
    float*  part   = (float*) alloc((size_t)CB*12*4);
    float*  zbuf   = (float*) alloc((size_t)CB*Mdim*4);
    ushort* sumb   = (ushort*)alloc((size_t)CB*Vdim*2);
    float*  probsC = (float*) alloc((size_t)CB*4*4);
    int*    bidxC  = (int*)   alloc((size_t)CB*4);
    int*    flagl  = (int*)   alloc((size_t)CB*4);
    int*    flagc  = (int*)   alloc(256);
    float*  fH     = (float*) alloc((size_t)CB*HMd*4);
    float*  fck    = (float*) alloc((size_t)CB*Kdim*4);
    float*  fctx   = zbuf;            // alias: zbuf written only by summary GEMM (later)
    ushort* zh     = (ushort*)zbuf;   // fp16 z view

    dim3 blk(256);
    dim3 blk512(512);
    const size_t LDS256 = 131072;
    // ---------- prep ----------
    k_cvt<<<(int)(((size_t)Bsz*Cdim/4 + 255)/256), blk, 0, stream>>>(ctx, ctxh, (size_t)Bsz*Cdim/4);
    k_wt<<<dim3(HMd/64,  Cdim/64), blk, 0, stream>>>(Wk1, W1m,             Cdim, HMd);
    k_wt<<<dim3(HMd/64,  Cdim/64), blk, 0, stream>>>(Wv1, W1m + 512*Cdim,  Cdim, HMd);
    k_wt<<<dim3(Kdim/64, HMd/64),  blk, 0, stream>>>(Wk2, W2m,             HMd, Kdim);
    k_wt<<<dim3(Vdim/64, HMd/64),  blk, 0, stream>>>(Wv2, W2m + 128*HMd,   HMd, Vdim);
    k_wt<<<dim3(Mdim/64, Vdim/64), blk, 0, stream>>>(Wsum, Wsumt, Vdim, Mdim);
    k_wg1t<<<dim3(384/64, GPAD/64, 4), blk, 0, stream>>>(Wg1, Wg1tt);
    k_cat<<<(1024+255)/256, blk, 0, stream>>>(biasm1, bk1, bv1, 512, 1024);
    k_cat<<<(384+255)/256,  blk, 0, stream>>>(biasm2, bk2, bv2, 128, 384);

    for (int b0 = 0; b0 < Bsz; b0 += CB){
        k_zero<<<1, blk, 0, stream>>>(flagc);
        // merged L1: H = gelu(ctx @ [Wk1|Wv1] + [bk1|bv1]), fp16 out — 256² 8-phase
        k_mgemm256<1,1,0,4><<<dim3(4, CB/256), blk512, LDS256, stream>>>(
            ctxh + (size_t)b0*Cdim, nullptr, W1m, biasm1, nullptr, H, Cdim, Cdim);
        // merged L2: ckv = [Hk@Wk2+bk2 | Hv@Wv2+bv2], f32 out — 128² (N=384)
        k_mgemm<0,0,2,3><<<dim3(3, CB/128), blk, 0, stream>>>(
            H, nullptr, W2m, biasm2, nullptr, ckv, HMd, 1024);
        // slot match + feats2 + flags
        k_feats<<<CB/4, blk, 0, stream>>>(ledger, keys, values, age, alive,
                                          ckv, ckc, feats2, bidxC, flagc, flagl, b0);
        // exact f32 recompute of ambiguous rows
        k_gather<<<CB/4, blk, 0, stream>>>(ctx, flagl, flagc, fctx, b0);
        k_gemm_dyn<1><<<dim3(HMd/64,  CB/64), blk, 0, stream>>>(fctx, Wk1, bk1, fH,  flagc, HMd,  Cdim);
        k_gemm_dyn<0><<<dim3(Kdim/64, CB/64), blk, 0, stream>>>(fH,   Wk2, bk2, fck, flagc, Kdim, HMd);
        k_fixapply<<<CB/4, blk, 0, stream>>>(fck, keys, values, age, alive,
                                             ckc, feats2, bidxC, flagc, flagl, b0);
        // gate GEMM with fused head: part[b,12] — 256² 8-phase
        k_mgemm256<0,2,1,6><<<dim3(6, CB/256), blk512, LDS256, stream>>>(
            ctxh + (size_t)b0*Cdim, feats2, Wg1tt, bg1, Wg2, part, GPAD, 0);
        // gates + scatter update + summary
        k_update<<<CB/4, blk, 0, stream>>>(keys, values, conf, age, alive, ckc, ckv,
                                           part, bg2, bidxC, probsC,
                                           o_keys, o_vals, o_conf, o_age, o_aliv,
                                           o_sum, sumb, b0);
        // summary projection (fp16 z out) — 256² 8-phase, then LN + promote
        k_mgemm256<0,1,0,4><<<dim3(4, CB/256), blk512, LDS256, stream>>>(
            sumb, nullptr, Wsumt, bsum, nullptr, zh, Vdim, Vdim);
        k_ln<<<CB, blk, 0, stream>>>(zh, probsC, g_ln, b_ln, o_prom, b0);
    }
}

// Round 8
// 500.699 us; speedup vs baseline: 1.2934x; 1.2934x over previous
//
#include <hip/hip_runtime.h>
#include <math.h>

static constexpr int Bsz  = 16384;
static constexpr int Cdim = 1024;
static constexpr int Kdim = 128;
static constexpr int Vdim = 256;
static constexpr int HMd  = 512;
static constexpr int GOUTd= 1536;   // 4*384 gate hidden
static constexpr int GDIM = 1669;
static constexpr int GPAD = 1728;   // 1024 (ctx) + 704 (feats2)
static constexpr int F2D  = 704;    // feats2 width = 11*64
static constexpr int Mdim = 1024;
static constexpr float TAU = 2e-3f; // fp16 score-gap ambiguity threshold (~13 sigma)

typedef __attribute__((ext_vector_type(8))) _Float16 f16x8;
typedef __attribute__((ext_vector_type(4))) _Float16 f16x4;
typedef __attribute__((ext_vector_type(4))) float f32x4;

__device__ __forceinline__ float sigm(float x){ return 1.0f/(1.0f+__expf(-x)); }
// exact-class gelu: erf via A&S 7.1.26 (max erf err 1.5e-7, far below fp16 rounding)
__device__ __forceinline__ float gelu(float x){
    float y = 0.70710678118654752440f * x;
    float a = fabsf(y);
    float t1 = __builtin_amdgcn_rcpf(fmaf(0.3275911f, a, 1.0f));
    float p = t1*fmaf(t1, fmaf(t1, fmaf(t1, fmaf(t1, 1.061405429f, -1.453152027f),
                                         1.421413741f), -0.284496736f), 0.254829592f);
    float e = __expf(-a*a);
    float er = fmaf(-p, e, 1.0f);
    er = (y < 0.0f) ? -er : er;
    return 0.5f*x*(1.0f+er);
}
__device__ __forceinline__ ushort f2h(float f){
    return __builtin_bit_cast(ushort, (_Float16)f);
}

// ============================ prep kernels ============================

__global__ __launch_bounds__(256) void k_zero(int* p){ if (threadIdx.x==0) *p = 0; }

__global__ __launch_bounds__(256) void k_cat(float* __restrict__ dst,
        const float* __restrict__ a, const float* __restrict__ b, int na, int ntot){
    int i = blockIdx.x*256 + threadIdx.x;
    if (i >= ntot) return;
    dst[i] = (i < na) ? a[i] : b[i-na];
}

// f32 [K,N] -> fp16 [N,K] tiled transpose
__global__ __launch_bounds__(256) void k_wt(const float* __restrict__ W,
                                            ushort* __restrict__ Wt, int K, int N){
    __shared__ float tile[64][65];
    int n0 = blockIdx.x*64, k0 = blockIdx.y*64;
    int tx = threadIdx.x & 63, ty = threadIdx.x >> 6;
    #pragma unroll
    for (int i=0;i<64;i+=4)
        tile[ty+i][tx] = W[(size_t)(k0+ty+i)*N + n0 + tx];
    __syncthreads();
    #pragma unroll
    for (int i=0;i<64;i+=4)
        Wt[(size_t)(n0+ty+i)*K + k0 + tx] = f2h(tile[tx][ty+i]);
}

// Wg1 (4,1669,384) -> fp16 [1536, 1728]
__global__ __launch_bounds__(256) void k_wg1t(const float* __restrict__ Wg1,
                                              ushort* __restrict__ Wt){
    __shared__ float tile[64][65];
    int g = blockIdx.z;
    int h0 = blockIdx.x*64, f0 = blockIdx.y*64;
    int tx = threadIdx.x & 63, ty = threadIdx.x >> 6;
    #pragma unroll
    for (int i=0;i<64;i+=4){
        int f = f0+ty+i;
        tile[ty+i][tx] = (f < GDIM) ? Wg1[((size_t)g*GDIM+f)*384 + h0+tx] : 0.0f;
    }
    __syncthreads();
    #pragma unroll
    for (int i=0;i<64;i+=4)
        Wt[((size_t)(g*384 + h0+ty+i))*GPAD + f0+tx] = f2h(tile[tx][ty+i]);
}

// f32 -> fp16 vectorized
__global__ __launch_bounds__(256) void k_cvt(const float* __restrict__ x,
                                             ushort* __restrict__ y, size_t n4){
    size_t i = (size_t)blockIdx.x*256 + threadIdx.x;
    if (i >= n4) return;
    float4 v = ((const float4*)x)[i];
    ushort4 o = { f2h(v.x), f2h(v.y), f2h(v.z), f2h(v.w) };
    ((ushort4*)y)[i] = o;
}

__device__ __forceinline__ void gload_lds16(const void* g, void* l){
    typedef __attribute__((address_space(1))) const unsigned gu32;
    typedef __attribute__((address_space(3))) unsigned lu32;
    __builtin_amdgcn_global_load_lds((gu32*)(unsigned long long)g,
                                     (lu32*)(unsigned)(unsigned long long)l,
                                     16, 0, 0);
}

// ============================ fp16 MFMA GEMM: 128x128 tile, 8 waves ============================
// 512 threads, single 32KB LDS buffer (max occupancy: 4 blocks x 8 waves = 32 waves/CU),
// proven r5 sync structure (__syncthreads, compiler waitcnts), XOR-swizzled LDS,
// XCD-bijective block swizzle. Wave wv: rows wr2=wv>>2 (64-row half), cols wc4=wv&3 (32-col strip).
// OUTM: 0 = f32 out, 1 = fp16 out, 2 = gate-fused head (part[row][bx], 128-col block in one gate)
// SRC : 0 = plain (stride lda), 1 = dual source (k<1024 from A stride 1024, else A2 stride 704),
//       2 = L2 col-select (A col offset 512 for bx>0)
template<int ACT, int OUTM, int SRC, int NX>
__global__ __launch_bounds__(512) void k_mgemm(const ushort* __restrict__ A,
        const ushort* __restrict__ A2, const ushort* __restrict__ Bt,
        const float* __restrict__ bias, const float* __restrict__ Wg2,
        void* __restrict__ Cout, int K, int lda){
    __shared__ alignas(16) ushort lds[16384];   // As[128][64] + Bs[128][64]
    ushort* As = lds;
    ushort* Bs = lds + 8192;
    int t = threadIdx.x;
    int l = t & 63, wv = t >> 6;
    int wr2 = wv >> 2, wc4 = wv & 3;
    // XCD-aware bijective swizzle (m204)
    int nwg = NX * (int)gridDim.y;
    int orig = (int)blockIdx.y * NX + (int)blockIdx.x;
    int qq = nwg >> 3, rr = nwg & 7;
    int xcd = orig & 7, loc = orig >> 3;
    int wgid = (xcd < rr ? xcd*(qq+1) : rr*(qq+1) + (xcd-rr)*qq) + loc;
    int bx = wgid % NX;
    int by = wgid / NX;
    size_t row0 = (size_t)by * 128;
    int col0 = bx * 128;
    constexpr int N = NX*128;
    f32x4 acc[4][2] = {};    // 4 row-frags x 2 col-frags per wave
    int lrow = l >> 3;
    int lc8  = (l & 7) ^ lrow;

    for (int k0 = 0; k0 < K; k0 += 64){
        const ushort* Ag; size_t astr; int koff;
        if (SRC == 1){
            if (k0 < 1024){ Ag = A;  astr = 1024; koff = k0; }
            else          { Ag = A2; astr = F2D;  koff = k0 - 1024; }
        } else if (SRC == 2){
            Ag = A; astr = (size_t)lda; koff = k0 + (bx ? 512 : 0);
        } else { Ag = A; astr = (size_t)lda; koff = k0; }
        #pragma unroll
        for (int i = 0; i < 2; ++i){
            int ch = wv*2 + i;                  // 0..15
            int r  = ch*8 + lrow;               // 0..127
            gload_lds16(Ag + (row0 + r)*astr + koff + lc8*8, As + ch*512);
            gload_lds16(Bt + (size_t)(col0 + r)*K + k0 + lc8*8, Bs + ch*512);
        }
        __syncthreads();
        #pragma unroll
        for (int kk = 0; kk < 2; ++kk){
            f16x8 af[4], bfr[2];
            int j8 = kk*4 + (l >> 4);
            #pragma unroll
            for (int m = 0; m < 4; ++m){
                int row = wr2*64 + m*16 + (l & 15);
                int c16 = j8 ^ (row & 7);
                af[m] = *(const f16x8*)(const void*)(As + row*64 + c16*8);
            }
            #pragma unroll
            for (int n = 0; n < 2; ++n){
                int rowb = wc4*32 + n*16 + (l & 15);
                int c16 = j8 ^ (rowb & 7);
                bfr[n] = *(const f16x8*)(const void*)(Bs + rowb*64 + c16*8);
            }
            #pragma unroll
            for (int m = 0; m < 4; ++m)
                #pragma unroll
                for (int n = 0; n < 2; ++n)
                    acc[m][n] = __builtin_amdgcn_mfma_f32_16x16x32_f16(af[m], bfr[n], acc[m][n], 0, 0, 0);
        }
        __syncthreads();
    }
    // C/D layout: col = l&15, row = (l>>4)*4 + i (m89-verified)
    int q = l >> 4, cf = l & 15;
    if (OUTM == 2){
        // fused gate head: 128-col block lies in exactly one gate (384 = 3*128)
        float* sacc = (float*)lds;              // [128] f32
        if (t < 128) sacc[t] = 0.f;
        __syncthreads();
        #pragma unroll
        for (int m = 0; m < 4; ++m){
            #pragma unroll
            for (int i = 0; i < 4; ++i){
                float v = 0.f;
                #pragma unroll
                for (int n = 0; n < 2; ++n){
                    int col = col0 + wc4*32 + n*16 + cf;
                    float z = acc[m][n][i] + bias[col];
                    v += gelu(z) * Wg2[col];
                }
                atomicAdd(&sacc[wr2*64 + m*16 + q*4 + i], v);
            }
        }
        __syncthreads();
        if (t < 128) ((float*)Cout)[(row0 + t)*NX + bx] = sacc[t];
    } else {
        #pragma unroll
        for (int m = 0; m < 4; ++m){
            #pragma unroll
            for (int n = 0; n < 2; ++n){
                int col = col0 + wc4*32 + n*16 + cf;
                float bv = bias[col];
                #pragma unroll
                for (int i = 0; i < 4; ++i){
                    size_t r = row0 + wr2*64 + m*16 + q*4 + i;
                    float v = acc[m][n][i] + bv;
                    if (ACT == 1) v = gelu(v);
                    if (OUTM == 1) ((ushort*)Cout)[r*N + col] = f2h(v);
                    else           ((float*) Cout)[r*N + col] = v;
                }
            }
        }
    }
}

// ============================ f32 GEMM, dynamic M (fix path) ============================
template<int ACT>
__global__ __launch_bounds__(256) void k_gemm_dyn(const float* __restrict__ A,
                                                  const float* __restrict__ W,
                                                  const float* __restrict__ bias,
                                                  float* __restrict__ C,
                                                  const int* __restrict__ cntp,
                                                  int N, int K){
    int M = (*cntp + 63) & ~63;
    size_t row0 = (size_t)blockIdx.y * 64;
    if ((int)row0 >= M) return;
    __shared__ float As[32][68];
    __shared__ float Ws[32][64];
    int t  = threadIdx.x;
    int tx = t & 15, ty = t >> 4;
    int col0 = blockIdx.x * 64;
    float acc[4][4] = {};
    int ra = t >> 3;
    int ca = (t & 7) << 2;
    int rw = t >> 4;
    int cw = (t & 15) << 2;
    for (int k0 = 0; k0 < K; k0 += 32){
        float4 a0 = *(const float4*)(A + (row0 + ra)*K + k0 + ca);
        float4 a1 = *(const float4*)(A + (row0 + ra + 32)*K + k0 + ca);
        float4 w0 = *(const float4*)(W + (size_t)(k0 + rw)*N + col0 + cw);
        float4 w1 = *(const float4*)(W + (size_t)(k0 + rw + 16)*N + col0 + cw);
        As[ca+0][ra] = a0.x; As[ca+1][ra] = a0.y; As[ca+2][ra] = a0.z; As[ca+3][ra] = a0.w;
        As[ca+0][ra+32] = a1.x; As[ca+1][ra+32] = a1.y; As[ca+2][ra+32] = a1.z; As[ca+3][ra+32] = a1.w;
        *(float4*)&Ws[rw][cw]    = w0;
        *(float4*)&Ws[rw+16][cw] = w1;
        __syncthreads();
        #pragma unroll
        for (int kk = 0; kk < 32; ++kk){
            float4 av = *(const float4*)&As[kk][ty*4];
            float4 wv = *(const float4*)&Ws[kk][tx*4];
            float a4[4] = {av.x, av.y, av.z, av.w};
            float w4[4] = {wv.x, wv.y, wv.z, wv.w};
            #pragma unroll
            for (int i=0;i<4;i++)
                #pragma unroll
                for (int j=0;j<4;j++)
                    acc[i][j] = fmaf(a4[i], w4[j], acc[i][j]);
        }
        __syncthreads();
    }
    #pragma unroll
    for (int i=0;i<4;i++){
        size_t r = row0 + ty*4 + i;
        #pragma unroll
        for (int j=0;j<4;j++){
            int c = col0 + tx*4 + j;
            float v = acc[i][j] + bias[c];
            if (ACT == 1) v = gelu(v);
            C[r*N + c] = v;
        }
    }
}

// gather flagged ctx rows -> fctx (f32), zero-pad to multiple of 64 rows
__global__ __launch_bounds__(256) void k_gather(const float* __restrict__ ctx,
        const int* __restrict__ flaglist, const int* __restrict__ flagcnt,
        float* __restrict__ fctx, int b0){
    int i = (blockIdx.x<<2) + (threadIdx.x>>6);
    int lane = threadIdx.x & 63;
    int cnt = *flagcnt;
    int cntpad = (cnt + 63) & ~63;
    if (i >= cntpad) return;
    float4* dst = (float4*)(fctx + (size_t)i*1024);
    if (i < cnt){
        const float4* src = (const float4*)(ctx + ((size_t)b0 + flaglist[i])*1024);
        #pragma unroll
        for (int j=0;j<4;j++) dst[lane + 64*j] = src[lane + 64*j];
    } else {
        float4 z = {0.f,0.f,0.f,0.f};
        #pragma unroll
        for (int j=0;j<4;j++) dst[lane + 64*j] = z;
    }
}

// per flagged row: normalize exact ck, rescore, patch ckc/feats2/bidx
__global__ __launch_bounds__(256) void k_fixapply(const float* __restrict__ fck,
        const float* __restrict__ keys, const float* __restrict__ values,
        const float* __restrict__ age,  const float* __restrict__ alive,
        float* __restrict__ ckc, ushort* __restrict__ feats2, int* __restrict__ bidx,
        const int* __restrict__ flagcnt, const int* __restrict__ flaglist, int b0){
    int i = (blockIdx.x<<2) + (threadIdx.x>>6);
    int lane = threadIdx.x & 63;
    if (i >= *flagcnt) return;
    int w = flaglist[i];
    size_t b = (size_t)b0 + w;
    float2 c2 = ((const float2*)(fck + (size_t)i*128))[lane];
    float ss = c2.x*c2.x + c2.y*c2.y;
    #pragma unroll
    for (int o=32;o;o>>=1) ss += __shfl_xor(ss,o);
    float inv = 1.0f / fmaxf(sqrtf(ss), 1e-6f);
    float2 cc; cc.x = c2.x*inv; cc.y = c2.y*inv;
    ((float2*)(ckc + (size_t)w*128))[lane] = cc;
    ushort* f2 = feats2 + (size_t)w*F2D;
    { ushort2 o = { f2h(cc.x), f2h(cc.y) };
      ((ushort2*)f2)[lane] = o; }
    float s1v = -1e30f; int bi = 0; int anylive = 0;
    #pragma unroll
    for (int s=0;s<6;s++){
        float a = alive[b*6+s];
        float2 k2 = ((const float2*)(keys + (b*6+s)*128))[lane];
        float ks = k2.x*k2.x + k2.y*k2.y;
        float dt = cc.x*k2.x + cc.y*k2.y;
        #pragma unroll
        for (int o=32;o;o>>=1){ ks += __shfl_xor(ks,o); dt += __shfl_xor(dt,o); }
        float sc;
        if (a > 0.0f){ sc = dt / fmaxf(sqrtf(ks), 1e-6f); anylive = 1; }
        else sc = -1e4f;
        if (sc > s1v){ s1v = sc; bi = s; }
    }
    int bis = anylive ? bi : 0;
    float bsc = anylive ? s1v : 0.0f;
    float4 mv = ((const float4*)(values + (b*6+bis)*256))[lane];
    ushort4 mo = { f2h(mv.x), f2h(mv.y), f2h(mv.z), f2h(mv.w) };
    ((ushort4*)(f2+384))[lane] = mo;
    if (lane == 0){
        bidx[w] = bis;
        float mage = age[b*6 + bis];
        f2[640] = f2h(bsc);
        f2[641] = f2h(sigm((mage - 8.0f)*0.125f));
        f2[642] = f2h(1.0f - bsc);
    }
}

// ---- slot match + feats2 build + ambiguity flagging ----
__global__ __launch_bounds__(256) void k_feats(
        const float* __restrict__ ledger, const float* __restrict__ keys,
        const float* __restrict__ values, const float* __restrict__ age,
        const float* __restrict__ alive,  const float* __restrict__ ckv,
        float* __restrict__ ckc, ushort* __restrict__ feats2,
        int* __restrict__ bidx, int* __restrict__ flagcnt, int* __restrict__ flaglist,
        int b0){
    int w = (blockIdx.x<<2) + (threadIdx.x>>6);
    int lane = threadIdx.x & 63;
    size_t b = (size_t)b0 + w;
    const float* ckr = ckv + (size_t)w*384;
    float2 cr2 = ((const float2*)ckr)[lane];
    float ssc = cr2.x*cr2.x + cr2.y*cr2.y;
    #pragma unroll
    for (int o=32;o;o>>=1) ssc += __shfl_xor(ssc,o);
    float invc = 1.0f / fmaxf(sqrtf(ssc), 1e-6f);
    float2 cc; cc.x = cr2.x*invc; cc.y = cr2.y*invc;
    ((float2*)(ckc + (size_t)w*128))[lane] = cc;
    float s1v = -1e30f, s2v = -1e30f; int bi = 0; int anylive = 0;
    #pragma unroll
    for (int s=0;s<6;s++){
        float a = alive[b*6+s];
        float2 k2 = ((const float2*)(keys + (b*6+s)*128))[lane];
        float ss = k2.x*k2.x + k2.y*k2.y;
        float dt = cc.x*k2.x + cc.y*k2.y;
        #pragma unroll
        for (int o=32;o;o>>=1){ ss += __shfl_xor(ss,o); dt += __shfl_xor(dt,o); }
        float sc;
        if (a > 0.0f){ sc = dt / fmaxf(sqrtf(ss), 1e-6f); anylive = 1; }
        else sc = -1e4f;
        if (sc > s1v){ s2v = s1v; s1v = sc; bi = s; }
        else if (sc > s2v) s2v = sc;
    }
    float best_score = anylive ? s1v : 0.0f;
    int bis = anylive ? bi : 0;
    if (lane == 0 && (s1v - s2v) < TAU){
        int pos = atomicAdd(flagcnt, 1);
        flaglist[pos] = w;
    }
    float4 mv = ((const float4*)(values + (b*6+bis)*256))[lane];
    float mage = age[b*6+bis];
    float cad = sigm((mage - 8.0f)*0.125f);
    ushort* f2 = feats2 + (size_t)w*F2D;
    { ushort2 o = { f2h(cc.x), f2h(cc.y) };
      ((ushort2*)f2)[lane] = o; }
    { float4 v = ((const float4*)(ckr+128))[lane];
      ushort4 o = { f2h(v.x), f2h(v.y), f2h(v.z), f2h(v.w) };
      ((ushort4*)(f2+128))[lane] = o; }
    { ushort4 o = { f2h(mv.x), f2h(mv.y), f2h(mv.z), f2h(mv.w) };
      ((ushort4*)(f2+384))[lane] = o; }
    if (lane == 0){
        f2[640] = f2h(best_score);
        f2[641] = f2h(cad);
        f2[642] = f2h(1.0f - best_score);
        f2[643] = f2h(ledger[b*2]);
        f2[644] = f2h(ledger[b*2+1]);
        bidx[w] = bis;
    }
    if (lane < GPAD - GDIM) f2[645+lane] = 0;
}

// ---- gates (from part), spawn select, scatter update, summary ----
// part layout: [row][12], j=bx (128-col block), gate g = j/3; probs = sigm(sum_j + bg2)
__global__ __launch_bounds__(256) void k_update(const float* __restrict__ keys,
        const float* __restrict__ values, const float* __restrict__ conf,
        const float* __restrict__ age,    const float* __restrict__ alive,
        const float* __restrict__ ckC,    const float* __restrict__ ckv,
        const float* __restrict__ part,   const float* __restrict__ bg2,
        const int* __restrict__ bidx,
        float* __restrict__ probsC,
        float* __restrict__ o_keys, float* __restrict__ o_vals,
        float* __restrict__ o_conf, float* __restrict__ o_age,
        float* __restrict__ o_aliv, float* __restrict__ o_sum,
        ushort* __restrict__ o_sumb, int b0){
    int w = (blockIdx.x<<2) + (threadIdx.x>>6);
    int lane = threadIdx.x & 63;
    size_t b = (size_t)b0 + w;
    const float* pp = part + (size_t)w*12;
    float pb[4];
    #pragma unroll
    for (int g=0; g<4; ++g)
        pb[g] = sigm(pp[3*g] + pp[3*g+1] + pp[3*g+2] + bg2[g]);
    if (lane < 4) probsC[w*4 + lane] = pb[lane];
    float rp = pb[0], sp = pb[1], tp = pb[3];
    float al[6], cf[6], ag[6];
    float hl = 0.f;
    #pragma unroll
    for (int s=0;s<6;s++){
        al[s]=alive[b*6+s]; cf[s]=conf[b*6+s]; ag[s]=age[b*6+s];
        hl = fmaxf(hl, al[s]);
    }
    float rr = hl * sigm((rp-0.55f)*4.0f);
    float sr = sigm((sp-0.60f)*4.0f);
    float den = 1.0f + rr + sr;
    float refresh = rr/den, spawn = sr/den;
    float retire = sigm((tp-0.15f)*4.0f);
    int bi = bidx[w];
    int ic = -1;
    #pragma unroll
    for (int s=5;s>=0;s--) if (al[s] < 0.5f) ic = s;
    int si;
    if (ic >= 0) si = ic;
    else {
        float bu = 1e30f; int am = 0;
        #pragma unroll
        for (int s=0;s<6;s++){
            float u = (s == bi) ? 1e4f : (cf[s] - 0.01f*ag[s]);
            if (u < bu){ bu = u; am = s; }
        }
        si = am;
    }
    float2 cc  = ((const float2*)(ckC + (size_t)w*128))[lane];
    float4 cvv = ((const float4*)(ckv + (size_t)w*384 + 128))[lane];
    float s0=0,s1=0,s2=0,s3=0, wsum=0;
    #pragma unroll
    for (int s=0;s<6;s++){
        float wr = refresh*(s==bi ? 1.0f:0.0f) + spawn*(s==si ? 1.0f:0.0f);
        wr = fminf(wr, 1.0f);
        float rs = (s==bi) ? retire : 0.0f;
        float om = 1.0f - wr;
        float2 k2 = ((const float2*)(keys + (b*6+s)*128))[lane];
        float2 kn; kn.x = k2.x*om + wr*cc.x; kn.y = k2.y*om + wr*cc.y;
        ((float2*)(o_keys + (b*6+s)*128))[lane] = kn;
        float4 vv = ((const float4*)(values + (b*6+s)*256))[lane];
        float4 vn;
        vn.x = vv.x*om + wr*cvv.x; vn.y = vv.y*om + wr*cvv.y;
        vn.z = vv.z*om + wr*cvv.z; vn.w = vv.w*om + wr*cvv.w;
        ((float4*)(o_vals + (b*6+s)*256))[lane] = vn;
        float cn  = (cf[s]*0.995f*om + wr) * (1.0f - rs);
        float an  = fminf(fmaxf(al[s]*(1.0f - rs) + wr, 0.0f), 1.0f);
        float agn = (ag[s] + al[s]) * om;
        float wgt = an * cn;
        wsum += wgt;
        s0 += vn.x*wgt; s1 += vn.y*wgt; s2 += vn.z*wgt; s3 += vn.w*wgt;
        if (lane == s){ o_conf[b*6+s] = cn; o_age[b*6+s] = agn; o_aliv[b*6+s] = an; }
    }
    float inv = 1.0f/(wsum + 1e-6f);
    float4 sm; sm.x = s0*inv; sm.y = s1*inv; sm.z = s2*inv; sm.w = s3*inv;
    ((float4*)(o_sum + b*256))[lane] = sm;
    ushort4 sb = { f2h(sm.x), f2h(sm.y), f2h(sm.z), f2h(sm.w) };
    ((ushort4*)(o_sumb + (size_t)w*256))[lane] = sb;
}

// ---- layernorm + promote (fp16 z in) ----
__global__ __launch_bounds__(256) void k_ln(const ushort* __restrict__ z,
        const float* __restrict__ probs, const float* __restrict__ g_ln,
        const float* __restrict__ b_ln,  float* __restrict__ o_prom, int b0){
    int w = blockIdx.x; int t = threadIdx.x;
    int lane = t & 63, wid = t >> 6;
    f16x4 hv = ((const f16x4*)(z + (size_t)w*1024))[t];
    float v0 = (float)hv[0], v1 = (float)hv[1], v2 = (float)hv[2], v3 = (float)hv[3];
    float s = v0+v1+v2+v3;
    #pragma unroll
    for (int o=32;o;o>>=1) s += __shfl_xor(s,o);
    __shared__ float red[4];
    if (lane==0) red[wid] = s;
    __syncthreads();
    float mu = (red[0]+red[1]+red[2]+red[3]) * (1.0f/1024.0f);
    float d0=v0-mu, d1=v1-mu, d2=v2-mu, d3=v3-mu;
    float ss = d0*d0+d1*d1+d2*d2+d3*d3;
    #pragma unroll
    for (int o=32;o;o>>=1) ss += __shfl_xor(ss,o);
    __syncthreads();
    if (lane==0) red[wid] = ss;
    __syncthreads();
    float var = (red[0]+red[1]+red[2]+red[3]) * (1.0f/1024.0f);
    float rstd = 1.0f / sqrtf(var + 1e-5f);
    float pm = sigm((probs[w*4+2]-0.50f)*4.0f);
    float4 g  = ((const float4*)g_ln)[t];
    float4 bb = ((const float4*)b_ln)[t];
    float4 o;
    o.x = pm*(d0*rstd*g.x + bb.x);
    o.y = pm*(d1*rstd*g.y + bb.y);
    o.z = pm*(d2*rstd*g.z + bb.z);
    o.w = pm*(d3*rstd*g.w + bb.w);
    ((float4*)(o_prom + ((size_t)b0 + w)*1024))[t] = o;
}

extern "C" void kernel_launch(void* const* d_in, const int* in_sizes, int n_in,
                              void* d_out, int out_size, void* d_ws, size_t ws_size,
                              hipStream_t stream){
    const float* ctx    = (const float*)d_in[0];
    const float* ledger = (const float*)d_in[1];
    const float* keys   = (const float*)d_in[2];
    const float* values = (const float*)d_in[3];
    const float* conf   = (const float*)d_in[4];
    const float* age    = (const float*)d_in[5];
    const float* alive  = (const float*)d_in[6];
    const float* Wk1 = (const float*)d_in[7];  const float* bk1 = (const float*)d_in[8];
    const float* Wk2 = (const float*)d_in[9];  const float* bk2 = (const float*)d_in[10];
    const float* Wv1 = (const float*)d_in[11]; const float* bv1 = (const float*)d_in[12];
    const float* Wv2 = (const float*)d_in[13]; const float* bv2 = (const float*)d_in[14];
    const float* Wg1 = (const float*)d_in[15]; const float* bg1 = (const float*)d_in[16];
    const float* Wg2 = (const float*)d_in[17]; const float* bg2 = (const float*)d_in[18];
    const float* Wsum= (const float*)d_in[19]; const float* bsum= (const float*)d_in[20];
    const float* g_ln= (const float*)d_in[21]; const float* b_ln= (const float*)d_in[22];

    float* out   = (float*)d_out;
    float* o_prom= out;
    float* o_sum = o_prom + (size_t)Bsz*Mdim;
    float* o_keys= o_sum  + (size_t)Bsz*Vdim;
    float* o_vals= o_keys + (size_t)Bsz*6*Kdim;
    float* o_conf= o_vals + (size_t)Bsz*6*Vdim;
    float* o_age = o_conf + (size_t)Bsz*6;
    float* o_aliv= o_age  + (size_t)Bsz*6;

    // ---------- workspace layout ----------
    char* p = (char*)d_ws;
    auto alloc = [&](size_t bytes)->char*{
        char* r = p; p += (bytes + 255) & ~(size_t)255; return r;
    };
    ushort* ctxh  = (ushort*)alloc((size_t)Bsz*Cdim*2);          // fp16 ctx
    ushort* W1m   = (ushort*)alloc((size_t)1024*Cdim*2);         // [Wk1t|Wv1t]
    ushort* W2m   = (ushort*)alloc((size_t)384*HMd*2);           // [Wk2t|Wv2t]
    ushort* Wg1tt = (ushort*)alloc((size_t)GOUTd*GPAD*2);
    ushort* Wsumt = (ushort*)alloc((size_t)Mdim*Vdim*2);
    float*  biasm1= (float*) alloc(1024*4);
    float*  biasm2= (float*) alloc(384*4);
    size_t fixed = (size_t)(p - (char*)d_ws);
    size_t per_row = 2048 + 1536 + 512 + 1408 + 48 + 4096 + 512 + 16
                   + 4 + 4 + 2048 + 512 + 128;
    int CB = 16384;
    while (CB > 256 && fixed + (size_t)CB*per_row + 16384 > ws_size) CB >>= 1;
    ushort* H      = (ushort*)alloc((size_t)CB*1024*2);   // [Hk|Hv] fp16
    float*  ckv    = (float*) alloc((size_t)CB*384*4);    // [ckraw|cv] f32
    float*  ckc    = (float*) alloc((size_t)CB*Kdim*4);
    ushort* feats2 = (ushort*)alloc((size_t)CB*F2D*2);
    float*  part   = (float*) alloc((size_t)CB*12*4);
    float*  zbuf   = (float*) alloc((size_t)CB*Mdim*4);
    ushort* sumb   = (ushort*)alloc((size_t)CB*Vdim*2);
    float*  probsC = (float*) alloc((size_t)CB*4*4);
    int*    bidxC  = (int*)   alloc((size_t)CB*4);
    int*    flagl  = (int*)   alloc((size_t)CB*4);
    int*    flagc  = (int*)   alloc(256);
    float*  fH     = (float*) alloc((size_t)CB*HMd*4);
    float*  fck    = (float*) alloc((size_t)CB*Kdim*4);
    float*  fctx   = zbuf;            // alias: zbuf written only by summary GEMM (later)
    ushort* zh     = (ushort*)zbuf;   // fp16 z view

    dim3 blk(256);
    dim3 blk512(512);
    // ---------- prep ----------
    k_cvt<<<(int)(((size_t)Bsz*Cdim/4 + 255)/256), blk, 0, stream>>>(ctx, ctxh, (size_t)Bsz*Cdim/4);
    k_wt<<<dim3(HMd/64,  Cdim/64), blk, 0, stream>>>(Wk1, W1m,             Cdim, HMd);
    k_wt<<<dim3(HMd/64,  Cdim/64), blk, 0, stream>>>(Wv1, W1m + 512*Cdim,  Cdim, HMd);
    k_wt<<<dim3(Kdim/64, HMd/64),  blk, 0, stream>>>(Wk2, W2m,             HMd, Kdim);
    k_wt<<<dim3(Vdim/64, HMd/64),  blk, 0, stream>>>(Wv2, W2m + 128*HMd,   HMd, Vdim);
    k_wt<<<dim3(Mdim/64, Vdim/64), blk, 0, stream>>>(Wsum, Wsumt, Vdim, Mdim);
    k_wg1t<<<dim3(384/64, GPAD/64, 4), blk, 0, stream>>>(Wg1, Wg1tt);
    k_cat<<<(1024+255)/256, blk, 0, stream>>>(biasm1, bk1, bv1, 512, 1024);
    k_cat<<<(384+255)/256,  blk, 0, stream>>>(biasm2, bk2, bv2, 128, 384);

    for (int b0 = 0; b0 < Bsz; b0 += CB){
        k_zero<<<1, blk, 0, stream>>>(flagc);
        // merged L1: H = gelu(ctx @ [Wk1|Wv1] + [bk1|bv1]), fp16 out
        k_mgemm<1,1,0,8><<<dim3(8, CB/128), blk512, 0, stream>>>(
            ctxh + (size_t)b0*Cdim, nullptr, W1m, biasm1, nullptr, H, Cdim, Cdim);
        // merged L2: ckv = [Hk@Wk2+bk2 | Hv@Wv2+bv2], f32 out
        k_mgemm<0,0,2,3><<<dim3(3, CB/128), blk512, 0, stream>>>(
            H, nullptr, W2m, biasm2, nullptr, ckv, HMd, 1024);
        // slot match + feats2 + flags
        k_feats<<<CB/4, blk, 0, stream>>>(ledger, keys, values, age, alive,
                                          ckv, ckc, feats2, bidxC, flagc, flagl, b0);
        // exact f32 recompute of ambiguous rows
        k_gather<<<CB/4, blk, 0, stream>>>(ctx, flagl, flagc, fctx, b0);
        k_gemm_dyn<1><<<dim3(HMd/64,  CB/64), blk, 0, stream>>>(fctx, Wk1, bk1, fH,  flagc, HMd,  Cdim);
        k_gemm_dyn<0><<<dim3(Kdim/64, CB/64), blk, 0, stream>>>(fH,   Wk2, bk2, fck, flagc, Kdim, HMd);
        k_fixapply<<<CB/4, blk, 0, stream>>>(fck, keys, values, age, alive,
                                             ckc, feats2, bidxC, flagc, flagl, b0);
        // gate GEMM with fused head: part[b,12]
        k_mgemm<0,2,1,12><<<dim3(12, CB/128), blk512, 0, stream>>>(
            ctxh + (size_t)b0*Cdim, feats2, Wg1tt, bg1, Wg2, part, GPAD, 0);
        // gates + scatter update + summary
        k_update<<<CB/4, blk, 0, stream>>>(keys, values, conf, age, alive, ckc, ckv,
                                           part, bg2, bidxC, probsC,
                                           o_keys, o_vals, o_conf, o_age, o_aliv,
                                           o_sum, sumb, b0);
        // summary projection (fp16 z out) + LN + promote
        k_mgemm<0,1,0,8><<<dim3(8, CB/128), blk512, 0, stream>>>(
            sumb, nullptr, Wsumt, bsum, nullptr, zh, Vdim, Vdim);
        k_ln<<<CB, blk, 0, stream>>>(zh, probsC, g_ln, b_ln, o_prom, b0);
    }
}

// Round 9
// 448.924 us; speedup vs baseline: 1.4426x; 1.1153x over previous
//
#include <hip/hip_runtime.h>
#include <math.h>

static constexpr int Bsz  = 16384;
static constexpr int Cdim = 1024;
static constexpr int Kdim = 128;
static constexpr int Vdim = 256;
static constexpr int HMd  = 512;
static constexpr int GOUTd= 1536;   // 4*384 gate hidden
static constexpr int GDIM = 1669;
static constexpr int GPAD = 1728;   // 1024 (ctx) + 704 (feats2)
static constexpr int F2D  = 704;    // feats2 width = 11*64
static constexpr int Mdim = 1024;
static constexpr float TAU = 2e-3f; // fp16 score-gap ambiguity threshold (~13 sigma)

typedef __attribute__((ext_vector_type(8))) _Float16 f16x8;
typedef __attribute__((ext_vector_type(4))) _Float16 f16x4;
typedef __attribute__((ext_vector_type(4))) float f32x4;

__device__ __forceinline__ float sigm(float x){ return 1.0f/(1.0f+__expf(-x)); }
// exact-class gelu: erf via A&S 7.1.26 (max erf err 1.5e-7, far below fp16 rounding)
__device__ __forceinline__ float gelu(float x){
    float y = 0.70710678118654752440f * x;
    float a = fabsf(y);
    float t1 = __builtin_amdgcn_rcpf(fmaf(0.3275911f, a, 1.0f));
    float p = t1*fmaf(t1, fmaf(t1, fmaf(t1, fmaf(t1, 1.061405429f, -1.453152027f),
                                         1.421413741f), -0.284496736f), 0.254829592f);
    float e = __expf(-a*a);
    float er = fmaf(-p, e, 1.0f);
    er = (y < 0.0f) ? -er : er;
    return 0.5f*x*(1.0f+er);
}
__device__ __forceinline__ ushort f2h(float f){
    return __builtin_bit_cast(ushort, (_Float16)f);
}

// ============================ prep kernels ============================

__global__ __launch_bounds__(256) void k_zero(int* p){ if (threadIdx.x==0) *p = 0; }

__global__ __launch_bounds__(256) void k_cat(float* __restrict__ dst,
        const float* __restrict__ a, const float* __restrict__ b, int na, int ntot){
    int i = blockIdx.x*256 + threadIdx.x;
    if (i >= ntot) return;
    dst[i] = (i < na) ? a[i] : b[i-na];
}

// f32 [K,N] -> fp16 [N,K] tiled transpose
__global__ __launch_bounds__(256) void k_wt(const float* __restrict__ W,
                                            ushort* __restrict__ Wt, int K, int N){
    __shared__ float tile[64][65];
    int n0 = blockIdx.x*64, k0 = blockIdx.y*64;
    int tx = threadIdx.x & 63, ty = threadIdx.x >> 6;
    #pragma unroll
    for (int i=0;i<64;i+=4)
        tile[ty+i][tx] = W[(size_t)(k0+ty+i)*N + n0 + tx];
    __syncthreads();
    #pragma unroll
    for (int i=0;i<64;i+=4)
        Wt[(size_t)(n0+ty+i)*K + k0 + tx] = f2h(tile[tx][ty+i]);
}

// Wg1 (4,1669,384) -> fp16 [1536, 1728]
__global__ __launch_bounds__(256) void k_wg1t(const float* __restrict__ Wg1,
                                              ushort* __restrict__ Wt){
    __shared__ float tile[64][65];
    int g = blockIdx.z;
    int h0 = blockIdx.x*64, f0 = blockIdx.y*64;
    int tx = threadIdx.x & 63, ty = threadIdx.x >> 6;
    #pragma unroll
    for (int i=0;i<64;i+=4){
        int f = f0+ty+i;
        tile[ty+i][tx] = (f < GDIM) ? Wg1[((size_t)g*GDIM+f)*384 + h0+tx] : 0.0f;
    }
    __syncthreads();
    #pragma unroll
    for (int i=0;i<64;i+=4)
        Wt[((size_t)(g*384 + h0+ty+i))*GPAD + f0+tx] = f2h(tile[tx][ty+i]);
}

// f32 -> fp16 vectorized
__global__ __launch_bounds__(256) void k_cvt(const float* __restrict__ x,
                                             ushort* __restrict__ y, size_t n4){
    size_t i = (size_t)blockIdx.x*256 + threadIdx.x;
    if (i >= n4) return;
    float4 v = ((const float4*)x)[i];
    ushort4 o = { f2h(v.x), f2h(v.y), f2h(v.z), f2h(v.w) };
    ((ushort4*)y)[i] = o;
}

__device__ __forceinline__ void gload_lds16(const void* g, void* l){
    typedef __attribute__((address_space(1))) const unsigned gu32;
    typedef __attribute__((address_space(3))) unsigned lu32;
    __builtin_amdgcn_global_load_lds((gu32*)(unsigned long long)g,
                                     (lu32*)(unsigned)(unsigned long long)l,
                                     16, 0, 0);
}

// ============================ fp16 MFMA GEMM: 256x128 tile, 8 waves ============================
// 512 threads, single 48KB LDS buffer (As[256][64] 32K + Bs[128][64] 16K), r5 sync structure
// (stage -> __syncthreads -> compute -> __syncthreads, compiler waitcnts), XOR-swizzled LDS,
// XCD-bijective block swizzle. Wave wv: wrow=wv>>1 (0..3, 64-row band), wcol=wv&1 (0..1, 64-col band).
// Per wave: 64x64 output = 4x4 frags, 32 MFMA + 16 ds_read_b128 per K-tile (r5's proven grain).
// __launch_bounds__(512,4): 4 waves/SIMD min => VGPR<=128 => 2 blocks/CU (16 waves).
// OUTM: 0 = f32 out, 1 = fp16 out, 2 = gate-fused head (part[row][bx], 128-col block in one gate)
// SRC : 0 = plain (stride lda), 1 = dual source (k<1024 from A stride 1024, else A2 stride 704),
//       2 = L2 col-select (A col offset 512 for bx>0)
template<int ACT, int OUTM, int SRC, int NX>
__global__ __launch_bounds__(512, 4) void k_mgemm(const ushort* __restrict__ A,
        const ushort* __restrict__ A2, const ushort* __restrict__ Bt,
        const float* __restrict__ bias, const float* __restrict__ Wg2,
        void* __restrict__ Cout, int K, int lda){
    __shared__ alignas(16) ushort lds[24576];   // As[256][64] + Bs[128][64]
    ushort* As = lds;
    ushort* Bs = lds + 16384;
    int t = threadIdx.x;
    int l = t & 63, wv = t >> 6;
    int wrow = wv >> 1, wcol = wv & 1;
    // XCD-aware bijective swizzle (m204)
    int nwg = NX * (int)gridDim.y;
    int orig = (int)blockIdx.y * NX + (int)blockIdx.x;
    int qq = nwg >> 3, rr = nwg & 7;
    int xcd = orig & 7, loc = orig >> 3;
    int wgid = (xcd < rr ? xcd*(qq+1) : rr*(qq+1) + (xcd-rr)*qq) + loc;
    int bx = wgid % NX;
    int by = wgid / NX;
    size_t row0 = (size_t)by * 256;
    int col0 = bx * 128;
    constexpr int N = NX*128;
    f32x4 acc[4][4] = {};
    int lrow = l >> 3;
    int lc8  = (l & 7) ^ lrow;

    for (int k0 = 0; k0 < K; k0 += 64){
        const ushort* Ag; size_t astr; int koff;
        if (SRC == 1){
            if (k0 < 1024){ Ag = A;  astr = 1024; koff = k0; }
            else          { Ag = A2; astr = F2D;  koff = k0 - 1024; }
        } else if (SRC == 2){
            Ag = A; astr = (size_t)lda; koff = k0 + (bx ? 512 : 0);
        } else { Ag = A; astr = (size_t)lda; koff = k0; }
        // stage A: 32 chunks of 8 rows; B: 16 chunks. 6 gloads/thread.
        #pragma unroll
        for (int i = 0; i < 4; ++i){
            int ch = wv*4 + i;                  // 0..31
            int r  = ch*8 + lrow;               // 0..255
            gload_lds16(Ag + (row0 + r)*astr + koff + lc8*8, As + ch*512);
        }
        #pragma unroll
        for (int i = 0; i < 2; ++i){
            int ch = wv*2 + i;                  // 0..15
            int r  = ch*8 + lrow;               // 0..127
            gload_lds16(Bt + (size_t)(col0 + r)*K + k0 + lc8*8, Bs + ch*512);
        }
        __syncthreads();
        #pragma unroll
        for (int kk = 0; kk < 2; ++kk){
            f16x8 af[4], bfr[4];
            int j8 = kk*4 + (l >> 4);
            #pragma unroll
            for (int m = 0; m < 4; ++m){
                int row = wrow*64 + m*16 + (l & 15);
                int c16 = j8 ^ (row & 7);
                af[m] = *(const f16x8*)(const void*)(As + row*64 + c16*8);
            }
            #pragma unroll
            for (int n = 0; n < 4; ++n){
                int rowb = wcol*64 + n*16 + (l & 15);
                int c16 = j8 ^ (rowb & 7);
                bfr[n] = *(const f16x8*)(const void*)(Bs + rowb*64 + c16*8);
            }
            #pragma unroll
            for (int m = 0; m < 4; ++m)
                #pragma unroll
                for (int n = 0; n < 4; ++n)
                    acc[m][n] = __builtin_amdgcn_mfma_f32_16x16x32_f16(af[m], bfr[n], acc[m][n], 0, 0, 0);
        }
        __syncthreads();
    }
    // C/D layout: col = l&15, row = (l>>4)*4 + i (m89-verified)
    int q = l >> 4, cf = l & 15;
    if (OUTM == 2){
        // fused gate head: 128-col block lies in exactly one gate (384 = 3*128)
        float* sacc = (float*)lds;              // [256] f32
        if (t < 256) sacc[t] = 0.f;
        __syncthreads();
        #pragma unroll
        for (int m = 0; m < 4; ++m){
            #pragma unroll
            for (int i = 0; i < 4; ++i){
                float v = 0.f;
                #pragma unroll
                for (int n = 0; n < 4; ++n){
                    int col = col0 + wcol*64 + n*16 + cf;
                    float z = acc[m][n][i] + bias[col];
                    v += gelu(z) * Wg2[col];
                }
                atomicAdd(&sacc[wrow*64 + m*16 + q*4 + i], v);
            }
        }
        __syncthreads();
        if (t < 256) ((float*)Cout)[(row0 + t)*NX + bx] = sacc[t];
    } else {
        #pragma unroll
        for (int m = 0; m < 4; ++m){
            #pragma unroll
            for (int n = 0; n < 4; ++n){
                int col = col0 + wcol*64 + n*16 + cf;
                float bv = bias[col];
                #pragma unroll
                for (int i = 0; i < 4; ++i){
                    size_t r = row0 + wrow*64 + m*16 + q*4 + i;
                    float v = acc[m][n][i] + bv;
                    if (ACT == 1) v = gelu(v);
                    if (OUTM == 1) ((ushort*)Cout)[r*N + col] = f2h(v);
                    else           ((float*) Cout)[r*N + col] = v;
                }
            }
        }
    }
}

// ============================ f32 GEMM, dynamic M (fix path) ============================
template<int ACT>
__global__ __launch_bounds__(256) void k_gemm_dyn(const float* __restrict__ A,
                                                  const float* __restrict__ W,
                                                  const float* __restrict__ bias,
                                                  float* __restrict__ C,
                                                  const int* __restrict__ cntp,
                                                  int N, int K){
    int M = (*cntp + 63) & ~63;
    size_t row0 = (size_t)blockIdx.y * 64;
    if ((int)row0 >= M) return;
    __shared__ float As[32][68];
    __shared__ float Ws[32][64];
    int t  = threadIdx.x;
    int tx = t & 15, ty = t >> 4;
    int col0 = blockIdx.x * 64;
    float acc[4][4] = {};
    int ra = t >> 3;
    int ca = (t & 7) << 2;
    int rw = t >> 4;
    int cw = (t & 15) << 2;
    for (int k0 = 0; k0 < K; k0 += 32){
        float4 a0 = *(const float4*)(A + (row0 + ra)*K + k0 + ca);
        float4 a1 = *(const float4*)(A + (row0 + ra + 32)*K + k0 + ca);
        float4 w0 = *(const float4*)(W + (size_t)(k0 + rw)*N + col0 + cw);
        float4 w1 = *(const float4*)(W + (size_t)(k0 + rw + 16)*N + col0 + cw);
        As[ca+0][ra] = a0.x; As[ca+1][ra] = a0.y; As[ca+2][ra] = a0.z; As[ca+3][ra] = a0.w;
        As[ca+0][ra+32] = a1.x; As[ca+1][ra+32] = a1.y; As[ca+2][ra+32] = a1.z; As[ca+3][ra+32] = a1.w;
        *(float4*)&Ws[rw][cw]    = w0;
        *(float4*)&Ws[rw+16][cw] = w1;
        __syncthreads();
        #pragma unroll
        for (int kk = 0; kk < 32; ++kk){
            float4 av = *(const float4*)&As[kk][ty*4];
            float4 wv = *(const float4*)&Ws[kk][tx*4];
            float a4[4] = {av.x, av.y, av.z, av.w};
            float w4[4] = {wv.x, wv.y, wv.z, wv.w};
            #pragma unroll
            for (int i=0;i<4;i++)
                #pragma unroll
                for (int j=0;j<4;j++)
                    acc[i][j] = fmaf(a4[i], w4[j], acc[i][j]);
        }
        __syncthreads();
    }
    #pragma unroll
    for (int i=0;i<4;i++){
        size_t r = row0 + ty*4 + i;
        #pragma unroll
        for (int j=0;j<4;j++){
            int c = col0 + tx*4 + j;
            float v = acc[i][j] + bias[c];
            if (ACT == 1) v = gelu(v);
            C[r*N + c] = v;
        }
    }
}

// gather flagged ctx rows -> fctx (f32), zero-pad to multiple of 64 rows
__global__ __launch_bounds__(256) void k_gather(const float* __restrict__ ctx,
        const int* __restrict__ flaglist, const int* __restrict__ flagcnt,
        float* __restrict__ fctx, int b0){
    int i = (blockIdx.x<<2) + (threadIdx.x>>6);
    int lane = threadIdx.x & 63;
    int cnt = *flagcnt;
    int cntpad = (cnt + 63) & ~63;
    if (i >= cntpad) return;
    float4* dst = (float4*)(fctx + (size_t)i*1024);
    if (i < cnt){
        const float4* src = (const float4*)(ctx + ((size_t)b0 + flaglist[i])*1024);
        #pragma unroll
        for (int j=0;j<4;j++) dst[lane + 64*j] = src[lane + 64*j];
    } else {
        float4 z = {0.f,0.f,0.f,0.f};
        #pragma unroll
        for (int j=0;j<4;j++) dst[lane + 64*j] = z;
    }
}

// per flagged row: normalize exact ck, rescore, patch ckc/feats2/bidx
__global__ __launch_bounds__(256) void k_fixapply(const float* __restrict__ fck,
        const float* __restrict__ keys, const float* __restrict__ values,
        const float* __restrict__ age,  const float* __restrict__ alive,
        float* __restrict__ ckc, ushort* __restrict__ feats2, int* __restrict__ bidx,
        const int* __restrict__ flagcnt, const int* __restrict__ flaglist, int b0){
    int i = (blockIdx.x<<2) + (threadIdx.x>>6);
    int lane = threadIdx.x & 63;
    if (i >= *flagcnt) return;
    int w = flaglist[i];
    size_t b = (size_t)b0 + w;
    float2 c2 = ((const float2*)(fck + (size_t)i*128))[lane];
    float ss = c2.x*c2.x + c2.y*c2.y;
    #pragma unroll
    for (int o=32;o;o>>=1) ss += __shfl_xor(ss,o);
    float inv = 1.0f / fmaxf(sqrtf(ss), 1e-6f);
    float2 cc; cc.x = c2.x*inv; cc.y = c2.y*inv;
    ((float2*)(ckc + (size_t)w*128))[lane] = cc;
    ushort* f2 = feats2 + (size_t)w*F2D;
    { ushort2 o = { f2h(cc.x), f2h(cc.y) };
      ((ushort2*)f2)[lane] = o; }
    float s1v = -1e30f; int bi = 0; int anylive = 0;
    #pragma unroll
    for (int s=0;s<6;s++){
        float a = alive[b*6+s];
        float2 k2 = ((const float2*)(keys + (b*6+s)*128))[lane];
        float ks = k2.x*k2.x + k2.y*k2.y;
        float dt = cc.x*k2.x + cc.y*k2.y;
        #pragma unroll
        for (int o=32;o;o>>=1){ ks += __shfl_xor(ks,o); dt += __shfl_xor(dt,o); }
        float sc;
        if (a > 0.0f){ sc = dt / fmaxf(sqrtf(ks), 1e-6f); anylive = 1; }
        else sc = -1e4f;
        if (sc > s1v){ s1v = sc; bi = s; }
    }
    int bis = anylive ? bi : 0;
    float bsc = anylive ? s1v : 0.0f;
    float4 mv = ((const float4*)(values + (b*6+bis)*256))[lane];
    ushort4 mo = { f2h(mv.x), f2h(mv.y), f2h(mv.z), f2h(mv.w) };
    ((ushort4*)(f2+384))[lane] = mo;
    if (lane == 0){
        bidx[w] = bis;
        float mage = age[b*6 + bis];
        f2[640] = f2h(bsc);
        f2[641] = f2h(sigm((mage - 8.0f)*0.125f));
        f2[642] = f2h(1.0f - bsc);
    }
}

// ---- slot match + feats2 build + ambiguity flagging ----
__global__ __launch_bounds__(256) void k_feats(
        const float* __restrict__ ledger, const float* __restrict__ keys,
        const float* __restrict__ values, const float* __restrict__ age,
        const float* __restrict__ alive,  const float* __restrict__ ckv,
        float* __restrict__ ckc, ushort* __restrict__ feats2,
        int* __restrict__ bidx, int* __restrict__ flagcnt, int* __restrict__ flaglist,
        int b0){
    int w = (blockIdx.x<<2) + (threadIdx.x>>6);
    int lane = threadIdx.x & 63;
    size_t b = (size_t)b0 + w;
    const float* ckr = ckv + (size_t)w*384;
    float2 cr2 = ((const float2*)ckr)[lane];
    float ssc = cr2.x*cr2.x + cr2.y*cr2.y;
    #pragma unroll
    for (int o=32;o;o>>=1) ssc += __shfl_xor(ssc,o);
    float invc = 1.0f / fmaxf(sqrtf(ssc), 1e-6f);
    float2 cc; cc.x = cr2.x*invc; cc.y = cr2.y*invc;
    ((float2*)(ckc + (size_t)w*128))[lane] = cc;
    float s1v = -1e30f, s2v = -1e30f; int bi = 0; int anylive = 0;
    #pragma unroll
    for (int s=0;s<6;s++){
        float a = alive[b*6+s];
        float2 k2 = ((const float2*)(keys + (b*6+s)*128))[lane];
        float ss = k2.x*k2.x + k2.y*k2.y;
        float dt = cc.x*k2.x + cc.y*k2.y;
        #pragma unroll
        for (int o=32;o;o>>=1){ ss += __shfl_xor(ss,o); dt += __shfl_xor(dt,o); }
        float sc;
        if (a > 0.0f){ sc = dt / fmaxf(sqrtf(ss), 1e-6f); anylive = 1; }
        else sc = -1e4f;
        if (sc > s1v){ s2v = s1v; s1v = sc; bi = s; }
        else if (sc > s2v) s2v = sc;
    }
    float best_score = anylive ? s1v : 0.0f;
    int bis = anylive ? bi : 0;
    if (lane == 0 && (s1v - s2v) < TAU){
        int pos = atomicAdd(flagcnt, 1);
        flaglist[pos] = w;
    }
    float4 mv = ((const float4*)(values + (b*6+bis)*256))[lane];
    float mage = age[b*6+bis];
    float cad = sigm((mage - 8.0f)*0.125f);
    ushort* f2 = feats2 + (size_t)w*F2D;
    { ushort2 o = { f2h(cc.x), f2h(cc.y) };
      ((ushort2*)f2)[lane] = o; }
    { float4 v = ((const float4*)(ckr+128))[lane];
      ushort4 o = { f2h(v.x), f2h(v.y), f2h(v.z), f2h(v.w) };
      ((ushort4*)(f2+128))[lane] = o; }
    { ushort4 o = { f2h(mv.x), f2h(mv.y), f2h(mv.z), f2h(mv.w) };
      ((ushort4*)(f2+384))[lane] = o; }
    if (lane == 0){
        f2[640] = f2h(best_score);
        f2[641] = f2h(cad);
        f2[642] = f2h(1.0f - best_score);
        f2[643] = f2h(ledger[b*2]);
        f2[644] = f2h(ledger[b*2+1]);
        bidx[w] = bis;
    }
    if (lane < GPAD - GDIM) f2[645+lane] = 0;
}

// ---- gates (from part), spawn select, scatter update, summary ----
// part layout: [row][12], j=bx (128-col block), gate g = j/3; probs = sigm(sum_j + bg2)
__global__ __launch_bounds__(256) void k_update(const float* __restrict__ keys,
        const float* __restrict__ values, const float* __restrict__ conf,
        const float* __restrict__ age,    const float* __restrict__ alive,
        const float* __restrict__ ckC,    const float* __restrict__ ckv,
        const float* __restrict__ part,   const float* __restrict__ bg2,
        const int* __restrict__ bidx,
        float* __restrict__ probsC,
        float* __restrict__ o_keys, float* __restrict__ o_vals,
        float* __restrict__ o_conf, float* __restrict__ o_age,
        float* __restrict__ o_aliv, float* __restrict__ o_sum,
        ushort* __restrict__ o_sumb, int b0){
    int w = (blockIdx.x<<2) + (threadIdx.x>>6);
    int lane = threadIdx.x & 63;
    size_t b = (size_t)b0 + w;
    const float* pp = part + (size_t)w*12;
    float pb[4];
    #pragma unroll
    for (int g=0; g<4; ++g)
        pb[g] = sigm(pp[3*g] + pp[3*g+1] + pp[3*g+2] + bg2[g]);
    if (lane < 4) probsC[w*4 + lane] = pb[lane];
    float rp = pb[0], sp = pb[1], tp = pb[3];
    float al[6], cf[6], ag[6];
    float hl = 0.f;
    #pragma unroll
    for (int s=0;s<6;s++){
        al[s]=alive[b*6+s]; cf[s]=conf[b*6+s]; ag[s]=age[b*6+s];
        hl = fmaxf(hl, al[s]);
    }
    float rr = hl * sigm((rp-0.55f)*4.0f);
    float sr = sigm((sp-0.60f)*4.0f);
    float den = 1.0f + rr + sr;
    float refresh = rr/den, spawn = sr/den;
    float retire = sigm((tp-0.15f)*4.0f);
    int bi = bidx[w];
    int ic = -1;
    #pragma unroll
    for (int s=5;s>=0;s--) if (al[s] < 0.5f) ic = s;
    int si;
    if (ic >= 0) si = ic;
    else {
        float bu = 1e30f; int am = 0;
        #pragma unroll
        for (int s=0;s<6;s++){
            float u = (s == bi) ? 1e4f : (cf[s] - 0.01f*ag[s]);
            if (u < bu){ bu = u; am = s; }
        }
        si = am;
    }
    float2 cc  = ((const float2*)(ckC + (size_t)w*128))[lane];
    float4 cvv = ((const float4*)(ckv + (size_t)w*384 + 128))[lane];
    float s0=0,s1=0,s2=0,s3=0, wsum=0;
    #pragma unroll
    for (int s=0;s<6;s++){
        float wr = refresh*(s==bi ? 1.0f:0.0f) + spawn*(s==si ? 1.0f:0.0f);
        wr = fminf(wr, 1.0f);
        float rs = (s==bi) ? retire : 0.0f;
        float om = 1.0f - wr;
        float2 k2 = ((const float2*)(keys + (b*6+s)*128))[lane];
        float2 kn; kn.x = k2.x*om + wr*cc.x; kn.y = k2.y*om + wr*cc.y;
        ((float2*)(o_keys + (b*6+s)*128))[lane] = kn;
        float4 vv = ((const float4*)(values + (b*6+s)*256))[lane];
        float4 vn;
        vn.x = vv.x*om + wr*cvv.x; vn.y = vv.y*om + wr*cvv.y;
        vn.z = vv.z*om + wr*cvv.z; vn.w = vv.w*om + wr*cvv.w;
        ((float4*)(o_vals + (b*6+s)*256))[lane] = vn;
        float cn  = (cf[s]*0.995f*om + wr) * (1.0f - rs);
        float an  = fminf(fmaxf(al[s]*(1.0f - rs) + wr, 0.0f), 1.0f);
        float agn = (ag[s] + al[s]) * om;
        float wgt = an * cn;
        wsum += wgt;
        s0 += vn.x*wgt; s1 += vn.y*wgt; s2 += vn.z*wgt; s3 += vn.w*wgt;
        if (lane == s){ o_conf[b*6+s] = cn; o_age[b*6+s] = agn; o_aliv[b*6+s] = an; }
    }
    float inv = 1.0f/(wsum + 1e-6f);
    float4 sm; sm.x = s0*inv; sm.y = s1*inv; sm.z = s2*inv; sm.w = s3*inv;
    ((float4*)(o_sum + b*256))[lane] = sm;
    ushort4 sb = { f2h(sm.x), f2h(sm.y), f2h(sm.z), f2h(sm.w) };
    ((ushort4*)(o_sumb + (size_t)w*256))[lane] = sb;
}

// ---- layernorm + promote (fp16 z in) ----
__global__ __launch_bounds__(256) void k_ln(const ushort* __restrict__ z,
        const float* __restrict__ probs, const float* __restrict__ g_ln,
        const float* __restrict__ b_ln,  float* __restrict__ o_prom, int b0){
    int w = blockIdx.x; int t = threadIdx.x;
    int lane = t & 63, wid = t >> 6;
    f16x4 hv = ((const f16x4*)(z + (size_t)w*1024))[t];
    float v0 = (float)hv[0], v1 = (float)hv[1], v2 = (float)hv[2], v3 = (float)hv[3];
    float s = v0+v1+v2+v3;
    #pragma unroll
    for (int o=32;o;o>>=1) s += __shfl_xor(s,o);
    __shared__ float red[4];
    if (lane==0) red[wid] = s;
    __syncthreads();
    float mu = (red[0]+red[1]+red[2]+red[3]) * (1.0f/1024.0f);
    float d0=v0-mu, d1=v1-mu, d2=v2-mu, d3=v3-mu;
    float ss = d0*d0+d1*d1+d2*d2+d3*d3;
    #pragma unroll
    for (int o=32;o;o>>=1) ss += __shfl_xor(ss,o);
    __syncthreads();
    if (lane==0) red[wid] = ss;
    __syncthreads();
    float var = (red[0]+red[1]+red[2]+red[3]) * (1.0f/1024.0f);
    float rstd = 1.0f / sqrtf(var + 1e-5f);
    float pm = sigm((probs[w*4+2]-0.50f)*4.0f);
    float4 g  = ((const float4*)g_ln)[t];
    float4 bb = ((const float4*)b_ln)[t];
    float4 o;
    o.x = pm*(d0*rstd*g.x + bb.x);
    o.y = pm*(d1*rstd*g.y + bb.y);
    o.z = pm*(d2*rstd*g.z + bb.z);
    o.w = pm*(d3*rstd*g.w + bb.w);
    ((float4*)(o_prom + ((size_t)b0 + w)*1024))[t] = o;
}

extern "C" void kernel_launch(void* const* d_in, const int* in_sizes, int n_in,
                              void* d_out, int out_size, void* d_ws, size_t ws_size,
                              hipStream_t stream){
    const float* ctx    = (const float*)d_in[0];
    const float* ledger = (const float*)d_in[1];
    const float* keys   = (const float*)d_in[2];
    const float* values = (const float*)d_in[3];
    const float* conf   = (const float*)d_in[4];
    const float* age    = (const float*)d_in[5];
    const float* alive  = (const float*)d_in[6];
    const float* Wk1 = (const float*)d_in[7];  const float* bk1 = (const float*)d_in[8];
    const float* Wk2 = (const float*)d_in[9];  const float* bk2 = (const float*)d_in[10];
    const float* Wv1 = (const float*)d_in[11]; const float* bv1 = (const float*)d_in[12];
    const float* Wv2 = (const float*)d_in[13]; const float* bv2 = (const float*)d_in[14];
    const float* Wg1 = (const float*)d_in[15]; const float* bg1 = (const float*)d_in[16];
    const float* Wg2 = (const float*)d_in[17]; const float* bg2 = (const float*)d_in[18];
    const float* Wsum= (const float*)d_in[19]; const float* bsum= (const float*)d_in[20];
    const float* g_ln= (const float*)d_in[21]; const float* b_ln= (const float*)d_in[22];

    float* out   = (float*)d_out;
    float* o_prom= out;
    float* o_sum = o_prom + (size_t)Bsz*Mdim;
    float* o_keys= o_sum  + (size_t)Bsz*Vdim;
    float* o_vals= o_keys + (size_t)Bsz*6*Kdim;
    float* o_conf= o_vals + (size_t)Bsz*6*Vdim;
    float* o_age = o_conf + (size_t)Bsz*6;
    float* o_aliv= o_age  + (size_t)Bsz*6;

    // ---------- workspace layout ----------
    char* p = (char*)d_ws;
    auto alloc = [&](size_t bytes)->char*{
        char* r = p; p += (bytes + 255) & ~(size_t)255; return r;
    };
    ushort* ctxh  = (ushort*)alloc((size_t)Bsz*Cdim*2);          // fp16 ctx
    ushort* W1m   = (ushort*)alloc((size_t)1024*Cdim*2);         // [Wk1t|Wv1t]
    ushort* W2m   = (ushort*)alloc((size_t)384*HMd*2);           // [Wk2t|Wv2t]
    ushort* Wg1tt = (ushort*)alloc((size_t)GOUTd*GPAD*2);
    ushort* Wsumt = (ushort*)alloc((size_t)Mdim*Vdim*2);
    float*  biasm1= (float*) alloc(1024*4);
    float*  biasm2= (float*) alloc(384*4);
    size_t fixed = (size_t)(p - (char*)d_ws);
    size_t per_row = 2048 + 1536 + 512 + 1408 + 48 + 4096 + 512 + 16
                   + 4 + 4 + 2048 + 512 + 128;
    int CB = 16384;
    while (CB > 256 && fixed + (size_t)CB*per_row + 16384 > ws_size) CB >>= 1;
    ushort* H      = (ushort*)alloc((size_t)CB*1024*2);   // [Hk|Hv] fp16
    float*  ckv    = (float*) alloc((size_t)CB*384*4);    // [ckraw|cv] f32
    float*  ckc    = (float*) alloc((size_t)CB*Kdim*4);
    ushort* feats2 = (ushort*)alloc((size_t)CB*F2D*2);
    float*  part   = (float*) alloc((size_t)CB*12*4);
    float*  zbuf   = (float*) alloc((size_t)CB*Mdim*4);
    ushort* sumb   = (ushort*)alloc((size_t)CB*Vdim*2);
    float*  probsC = (float*) alloc((size_t)CB*4*4);
    int*    bidxC  = (int*)   alloc((size_t)CB*4);
    int*    flagl  = (int*)   alloc((size_t)CB*4);
    int*    flagc  = (int*)   alloc(256);
    float*  fH     = (float*) alloc((size_t)CB*HMd*4);
    float*  fck    = (float*) alloc((size_t)CB*Kdim*4);
    float*  fctx   = zbuf;            // alias: zbuf written only by summary GEMM (later)
    ushort* zh     = (ushort*)zbuf;   // fp16 z view

    dim3 blk(256);
    dim3 blk512(512);
    // ---------- prep ----------
    k_cvt<<<(int)(((size_t)Bsz*Cdim/4 + 255)/256), blk, 0, stream>>>(ctx, ctxh, (size_t)Bsz*Cdim/4);
    k_wt<<<dim3(HMd/64,  Cdim/64), blk, 0, stream>>>(Wk1, W1m,             Cdim, HMd);
    k_wt<<<dim3(HMd/64,  Cdim/64), blk, 0, stream>>>(Wv1, W1m + 512*Cdim,  Cdim, HMd);
    k_wt<<<dim3(Kdim/64, HMd/64),  blk, 0, stream>>>(Wk2, W2m,             HMd, Kdim);
    k_wt<<<dim3(Vdim/64, HMd/64),  blk, 0, stream>>>(Wv2, W2m + 128*HMd,   HMd, Vdim);
    k_wt<<<dim3(Mdim/64, Vdim/64), blk, 0, stream>>>(Wsum, Wsumt, Vdim, Mdim);
    k_wg1t<<<dim3(384/64, GPAD/64, 4), blk, 0, stream>>>(Wg1, Wg1tt);
    k_cat<<<(1024+255)/256, blk, 0, stream>>>(biasm1, bk1, bv1, 512, 1024);
    k_cat<<<(384+255)/256,  blk, 0, stream>>>(biasm2, bk2, bv2, 128, 384);

    for (int b0 = 0; b0 < Bsz; b0 += CB){
        k_zero<<<1, blk, 0, stream>>>(flagc);
        // merged L1: H = gelu(ctx @ [Wk1|Wv1] + [bk1|bv1]), fp16 out
        k_mgemm<1,1,0,8><<<dim3(8, CB/256), blk512, 0, stream>>>(
            ctxh + (size_t)b0*Cdim, nullptr, W1m, biasm1, nullptr, H, Cdim, Cdim);
        // merged L2: ckv = [Hk@Wk2+bk2 | Hv@Wv2+bv2], f32 out
        k_mgemm<0,0,2,3><<<dim3(3, CB/256), blk512, 0, stream>>>(
            H, nullptr, W2m, biasm2, nullptr, ckv, HMd, 1024);
        // slot match + feats2 + flags
        k_feats<<<CB/4, blk, 0, stream>>>(ledger, keys, values, age, alive,
                                          ckv, ckc, feats2, bidxC, flagc, flagl, b0);
        // exact f32 recompute of ambiguous rows
        k_gather<<<CB/4, blk, 0, stream>>>(ctx, flagl, flagc, fctx, b0);
        k_gemm_dyn<1><<<dim3(HMd/64,  CB/64), blk, 0, stream>>>(fctx, Wk1, bk1, fH,  flagc, HMd,  Cdim);
        k_gemm_dyn<0><<<dim3(Kdim/64, CB/64), blk, 0, stream>>>(fH,   Wk2, bk2, fck, flagc, Kdim, HMd);
        k_fixapply<<<CB/4, blk, 0, stream>>>(fck, keys, values, age, alive,
                                             ckc, feats2, bidxC, flagc, flagl, b0);
        // gate GEMM with fused head: part[b,12]
        k_mgemm<0,2,1,12><<<dim3(12, CB/256), blk512, 0, stream>>>(
            ctxh + (size_t)b0*Cdim, feats2, Wg1tt, bg1, Wg2, part, GPAD, 0);
        // gates + scatter update + summary
        k_update<<<CB/4, blk, 0, stream>>>(keys, values, conf, age, alive, ckc, ckv,
                                           part, bg2, bidxC, probsC,
                                           o_keys, o_vals, o_conf, o_age, o_aliv,
                                           o_sum, sumb, b0);
        // summary projection (fp16 z out) + LN + promote
        k_mgemm<0,1,0,8><<<dim3(8, CB/256), blk512, 0, stream>>>(
            sumb, nullptr, Wsumt, bsum, nullptr, zh, Vdim, Vdim);
        k_ln<<<CB, blk, 0, stream>>>(zh, probsC, g_ln, b_ln, o_prom, b0);
    }
}